// Round 1
// baseline (1439.381 us; speedup 1.0000x reference)
//
#include <hip/hip_runtime.h>
#include <hip/hip_bf16.h>

typedef __bf16 bf16_t;
typedef float  f32x4  __attribute__((ext_vector_type(4)));
typedef bf16_t bf16x4 __attribute__((ext_vector_type(4)));
typedef bf16_t bf16x8 __attribute__((ext_vector_type(8)));
typedef int    i32x4  __attribute__((ext_vector_type(4)));

#define MFMA16(a, b, c) __builtin_amdgcn_mfma_f32_16x16x32_bf16((a), (b), (c), 0, 0, 0)

// ---------------- elementwise f32 -> bf16 ----------------
__global__ __launch_bounds__(256) void cvt_bf16(const float* __restrict__ in,
                                                bf16_t* __restrict__ out, int n4) {
  int stride = gridDim.x * blockDim.x;
  for (int i = blockIdx.x * blockDim.x + threadIdx.x; i < n4; i += stride) {
    f32x4 v = ((const f32x4*)in)[i];
    bf16x4 o;
#pragma unroll
    for (int j = 0; j < 4; ++j) o[j] = (bf16_t)v[j];
    ((bf16x4*)out)[i] = o;
  }
}

// ---------------- transpose + convert: in[R][C] f32 -> out[C][R] bf16 ----------------
__global__ __launch_bounds__(256) void transpose_cvt(const float* __restrict__ in,
                                                     bf16_t* __restrict__ out,
                                                     int R, int C) {
  __shared__ float t[64][65];
  int tr0 = blockIdx.y * 64, tc0 = blockIdx.x * 64;
  int tx = threadIdx.x & 15, ty = threadIdx.x >> 4;
#pragma unroll
  for (int i = 0; i < 4; ++i) {
    f32x4 v = *(const f32x4*)(in + (size_t)(tr0 + ty + 16 * i) * C + tc0 + tx * 4);
#pragma unroll
    for (int j = 0; j < 4; ++j) t[ty + 16 * i][tx * 4 + j] = v[j];
  }
  __syncthreads();
#pragma unroll
  for (int i = 0; i < 4; ++i) {
    bf16x4 o4;
#pragma unroll
    for (int j = 0; j < 4; ++j) o4[j] = (bf16_t)t[tx * 4 + j][ty + 16 * i];
    *(bf16x4*)(out + (size_t)(tc0 + ty + 16 * i) * R + tr0 + tx * 4) = o4;
  }
}

// ---------------- GEMM: C[M][N] = A[M][K] * Bt[N][K]^T  (bf16 in, f32 acc) ----------------
template <int WRITE_BF16>
__global__ __launch_bounds__(256) void gemm_bf16(const bf16_t* __restrict__ A,
                                                 const bf16_t* __restrict__ Bt,
                                                 void* __restrict__ Cv,
                                                 int M, int N, int K) {
  __shared__ alignas(16) bf16_t Al[128][72];
  __shared__ alignas(16) bf16_t Bl[128][72];
  const int tid = threadIdx.x;
  const int lane = tid & 63, wid = tid >> 6;
  const int wr = wid >> 1, wc = wid & 1;
  const int g = lane >> 4, ci = lane & 15;
  const int m0 = blockIdx.y * 128, n0 = blockIdx.x * 128;

  i32x4 ra[4], rb[4];
#pragma unroll
  for (int i = 0; i < 4; ++i) {
    int c = tid + i * 256;
    int row = c >> 3, kc = (c & 7) * 8;
    ra[i] = *(const i32x4*)(A + (size_t)(m0 + row) * K + kc);
    rb[i] = *(const i32x4*)(Bt + (size_t)(n0 + row) * K + kc);
  }
  f32x4 acc[4][4];
#pragma unroll
  for (int m = 0; m < 4; ++m)
#pragma unroll
    for (int n = 0; n < 4; ++n) acc[m][n] = f32x4{0.f, 0.f, 0.f, 0.f};

  for (int kt = 0; kt < K; kt += 64) {
    __syncthreads();
#pragma unroll
    for (int i = 0; i < 4; ++i) {
      int c = tid + i * 256;
      int row = c >> 3, kc = (c & 7) * 8;
      *(i32x4*)&Al[row][kc] = ra[i];
      *(i32x4*)&Bl[row][kc] = rb[i];
    }
    __syncthreads();
    if (kt + 64 < K) {
#pragma unroll
      for (int i = 0; i < 4; ++i) {
        int c = tid + i * 256;
        int row = c >> 3, kc = (c & 7) * 8;
        ra[i] = *(const i32x4*)(A + (size_t)(m0 + row) * K + kt + 64 + kc);
        rb[i] = *(const i32x4*)(Bt + (size_t)(n0 + row) * K + kt + 64 + kc);
      }
    }
#pragma unroll
    for (int ks = 0; ks < 2; ++ks) {
      bf16x8 af[4], bv[4];
#pragma unroll
      for (int m = 0; m < 4; ++m) {
        bf16x4 lo = *(const bf16x4*)&Al[wr * 64 + m * 16 + ci][ks * 32 + 4 * g];
        bf16x4 hi = *(const bf16x4*)&Al[wr * 64 + m * 16 + ci][ks * 32 + 16 + 4 * g];
        af[m] = __builtin_shufflevector(lo, hi, 0, 1, 2, 3, 4, 5, 6, 7);
      }
#pragma unroll
      for (int n = 0; n < 4; ++n) {
        bf16x4 lo = *(const bf16x4*)&Bl[wc * 64 + n * 16 + ci][ks * 32 + 4 * g];
        bf16x4 hi = *(const bf16x4*)&Bl[wc * 64 + n * 16 + ci][ks * 32 + 16 + 4 * g];
        bv[n] = __builtin_shufflevector(lo, hi, 0, 1, 2, 3, 4, 5, 6, 7);
      }
#pragma unroll
      for (int m = 0; m < 4; ++m)
#pragma unroll
        for (int n = 0; n < 4; ++n) acc[m][n] = MFMA16(af[m], bv[n], acc[m][n]);
    }
  }
  // epilogue: D row = (l>>4)*4 + r, col = l&15 (verified layout)
#pragma unroll
  for (int m = 0; m < 4; ++m) {
#pragma unroll
    for (int n = 0; n < 4; ++n) {
      int grow = m0 + wr * 64 + m * 16 + g * 4;
      int gcol = n0 + wc * 64 + n * 16 + ci;
#pragma unroll
      for (int r = 0; r < 4; ++r) {
        if (WRITE_BF16)
          ((bf16_t*)Cv)[(size_t)(grow + r) * N + gcol] = (bf16_t)acc[m][n][r];
        else
          ((float*)Cv)[(size_t)(grow + r) * N + gcol] = acc[m][n][r];
      }
    }
  }
}

// ---------------- RoPE + repack to [B,H,N,D] ----------------
__global__ __launch_bounds__(256) void rope_pack(const bf16_t* __restrict__ Qraw,
                                                 const bf16_t* __restrict__ Kraw,
                                                 const bf16_t* __restrict__ Vraw,
                                                 const int* __restrict__ pos,
                                                 bf16_t* __restrict__ Qr,
                                                 bf16_t* __restrict__ Kr,
                                                 bf16_t* __restrict__ Vr) {
  int unit = blockIdx.x * 4 + (threadIdx.x >> 6);
  int lane = threadIdx.x & 63;
  int token = unit / 48, slot = unit % 48;
  int b = token >> 11, n = token & 2047;
  if (slot < 40) {
    float p = (float)pos[token];
    float inv = powf(10000.0f, -(float)lane * (1.0f / 64.0f));
    float ang = p * inv;
    float cs = cosf(ang), sn = sinf(ang);
    const bf16_t* src;
    bf16_t* dst;
    if (slot < 32) {
      src = Qraw + (size_t)token * 4096 + slot * 128;
      dst = Qr + ((size_t)(b * 32 + slot) * 2048 + n) * 128;
    } else {
      int kvh = slot - 32;
      src = Kraw + (size_t)token * 1024 + kvh * 128;
      dst = Kr + ((size_t)(b * 8 + kvh) * 2048 + n) * 128;
    }
    float x0 = (float)src[lane], x1 = (float)src[lane + 64];
    dst[lane] = (bf16_t)(x0 * cs - x1 * sn);
    dst[lane + 64] = (bf16_t)(x1 * cs + x0 * sn);
  } else {
    int kvh = slot - 40;
    const bf16_t* src = Vraw + (size_t)token * 1024 + kvh * 128;
    bf16_t* dst = Vr + ((size_t)(b * 8 + kvh) * 2048 + n) * 128;
    dst[lane] = src[lane];
    dst[lane + 64] = src[lane + 64];
  }
}

// ---------------- flash attention: 1 wave per (head, 16 q rows) ----------------
__global__ __launch_bounds__(64) void attn_kernel(const bf16_t* __restrict__ Q,
                                                  const bf16_t* __restrict__ K,
                                                  const bf16_t* __restrict__ V,
                                                  bf16_t* __restrict__ O) {
  const float scale = 0.08838834764831845f;  // 1/sqrt(128)
  __shared__ alignas(16) bf16_t Pl[16][36];
  __shared__ alignas(16) bf16_t Vt[128][36];
  int lane = threadIdx.x;
  int g = lane >> 4, ci = lane & 15;
  int hb = blockIdx.y;  // 0..63 = b*32+h
  int b = hb >> 5, h = hb & 31, kvh = h >> 2;
  int n0 = blockIdx.x * 16;
  const bf16_t* Qh = Q + ((size_t)hb * 2048) * 128;
  const bf16_t* Kh = K + ((size_t)(b * 8 + kvh) * 2048) * 128;
  const bf16_t* Vh = V + ((size_t)(b * 8 + kvh) * 2048) * 128;

  bf16x8 aq[4];
  {
    const bf16_t* qp = Qh + (size_t)(n0 + ci) * 128;
#pragma unroll
    for (int ks = 0; ks < 4; ++ks) {
      bf16x4 lo = *(const bf16x4*)(qp + ks * 32 + 4 * g);
      bf16x4 hi = *(const bf16x4*)(qp + ks * 32 + 16 + 4 * g);
      aq[ks] = __builtin_shufflevector(lo, hi, 0, 1, 2, 3, 4, 5, 6, 7);
    }
  }
  f32x4 o[8];
#pragma unroll
  for (int nb = 0; nb < 8; ++nb) o[nb] = f32x4{0.f, 0.f, 0.f, 0.f};
  float mrow[4] = {-1e30f, -1e30f, -1e30f, -1e30f};
  float lrow[4] = {0.f, 0.f, 0.f, 0.f};

  int ktmax = (n0 + 15) >> 5;
  for (int kt = 0; kt <= ktmax; ++kt) {
    int m0k = kt * 32;
    f32x4 s[2];
#pragma unroll
    for (int cb = 0; cb < 2; ++cb) {
      s[cb] = f32x4{0.f, 0.f, 0.f, 0.f};
      const bf16_t* kp = Kh + (size_t)(m0k + cb * 16 + ci) * 128;
#pragma unroll
      for (int ks = 0; ks < 4; ++ks) {
        bf16x4 lo = *(const bf16x4*)(kp + ks * 32 + 4 * g);
        bf16x4 hi = *(const bf16x4*)(kp + ks * 32 + 16 + 4 * g);
        bf16x8 bk = __builtin_shufflevector(lo, hi, 0, 1, 2, 3, 4, 5, 6, 7);
        s[cb] = MFMA16(aq[ks], bk, s[cb]);
      }
    }
    // stage V tile (32 kv x 128 d) transposed -> Vt[d][kv]
    {
      int kb = lane >> 3;  // kv block: rows kb*4..+3
      int db = lane & 7;
#pragma unroll
      for (int t2 = 0; t2 < 2; ++t2) {
        int d0 = (db + 8 * t2) * 8;
        bf16x8 r0 = *(const bf16x8*)(Vh + (size_t)(m0k + kb * 4 + 0) * 128 + d0);
        bf16x8 r1 = *(const bf16x8*)(Vh + (size_t)(m0k + kb * 4 + 1) * 128 + d0);
        bf16x8 r2 = *(const bf16x8*)(Vh + (size_t)(m0k + kb * 4 + 2) * 128 + d0);
        bf16x8 r3 = *(const bf16x8*)(Vh + (size_t)(m0k + kb * 4 + 3) * 128 + d0);
#pragma unroll
        for (int j = 0; j < 8; ++j) {
          bf16x4 w;
          w[0] = r0[j]; w[1] = r1[j]; w[2] = r2[j]; w[3] = r3[j];
          *(bf16x4*)&Vt[d0 + j][kb * 4] = w;
        }
      }
    }
    // scale + causal mask (S row = n0 + g*4 + r, col = m0k + cb*16 + ci)
#pragma unroll
    for (int cb = 0; cb < 2; ++cb) {
      int col = m0k + cb * 16 + ci;
#pragma unroll
      for (int r = 0; r < 4; ++r) {
        float v = s[cb][r] * scale;
        if (col > n0 + g * 4 + r) v = -1e30f;
        s[cb][r] = v;
      }
    }
    // online softmax
#pragma unroll
    for (int r = 0; r < 4; ++r) {
      float mx = fmaxf(s[0][r], s[1][r]);
      mx = fmaxf(mx, __shfl_xor(mx, 1));
      mx = fmaxf(mx, __shfl_xor(mx, 2));
      mx = fmaxf(mx, __shfl_xor(mx, 4));
      mx = fmaxf(mx, __shfl_xor(mx, 8));
      float mnew = fmaxf(mrow[r], mx);
      float fs = __expf(mrow[r] - mnew);
      float p0 = __expf(s[0][r] - mnew);
      float p1 = __expf(s[1][r] - mnew);
      s[0][r] = p0; s[1][r] = p1;
      float ps = p0 + p1;
      ps += __shfl_xor(ps, 1);
      ps += __shfl_xor(ps, 2);
      ps += __shfl_xor(ps, 4);
      ps += __shfl_xor(ps, 8);
      lrow[r] = lrow[r] * fs + ps;
      mrow[r] = mnew;
#pragma unroll
      for (int nb = 0; nb < 8; ++nb) o[nb][r] *= fs;
    }
    // P -> LDS (D-layout -> [row][col])
#pragma unroll
    for (int cb = 0; cb < 2; ++cb)
#pragma unroll
      for (int r = 0; r < 4; ++r) Pl[g * 4 + r][cb * 16 + ci] = (bf16_t)s[cb][r];
    __syncthreads();
    // PV: A = P (row=l&15, k over kv), B = Vt (col=d, k over kv)
    bf16x8 pa;
    {
      bf16x4 lo = *(const bf16x4*)&Pl[ci][4 * g];
      bf16x4 hi = *(const bf16x4*)&Pl[ci][16 + 4 * g];
      pa = __builtin_shufflevector(lo, hi, 0, 1, 2, 3, 4, 5, 6, 7);
    }
#pragma unroll
    for (int nb = 0; nb < 8; ++nb) {
      int d = nb * 16 + ci;
      bf16x4 lo = *(const bf16x4*)&Vt[d][4 * g];
      bf16x4 hi = *(const bf16x4*)&Vt[d][16 + 4 * g];
      bf16x8 bvv = __builtin_shufflevector(lo, hi, 0, 1, 2, 3, 4, 5, 6, 7);
      o[nb] = MFMA16(pa, bvv, o[nb]);
    }
    __syncthreads();
  }
  // epilogue: O[token][h*128+d], token = b*2048 + n0 + g*4 + r
#pragma unroll
  for (int r = 0; r < 4; ++r) {
    float inv = 1.0f / lrow[r];
    int token = b * 2048 + n0 + g * 4 + r;
    bf16_t* op = O + (size_t)token * 4096 + h * 128;
#pragma unroll
    for (int nb = 0; nb < 8; ++nb) op[nb * 16 + ci] = (bf16_t)(o[nb][r] * inv);
  }
}

extern "C" void kernel_launch(void* const* d_in, const int* in_sizes, int n_in,
                              void* d_out, int out_size, void* d_ws, size_t ws_size,
                              hipStream_t stream) {
  (void)in_sizes; (void)n_in; (void)out_size; (void)ws_size;
  const float* X = (const float*)d_in[0];
  const int* pos = (const int*)d_in[1];
  const float* Wq = (const float*)d_in[2];
  const float* Wk = (const float*)d_in[3];
  const float* Wv = (const float*)d_in[4];
  const float* Wo = (const float*)d_in[5];
  float* out = (float*)d_out;

  char* w = (char*)d_ws;
  auto carve = [&](size_t bytes) {
    void* p = (void*)w;
    w += (bytes + 255) & ~(size_t)255;
    return p;
  };
  const size_t T = 4096;  // B*N tokens
  bf16_t* Xbf  = (bf16_t*)carve(T * 4096 * 2);
  bf16_t* WqT  = (bf16_t*)carve(4096ull * 4096 * 2);
  bf16_t* WkT  = (bf16_t*)carve(1024ull * 4096 * 2);
  bf16_t* WvT  = (bf16_t*)carve(1024ull * 4096 * 2);
  bf16_t* WoT  = (bf16_t*)carve(4096ull * 4096 * 2);
  bf16_t* Qraw = (bf16_t*)carve(T * 4096 * 2);
  bf16_t* Kraw = (bf16_t*)carve(T * 1024 * 2);
  bf16_t* Vraw = (bf16_t*)carve(T * 1024 * 2);
  bf16_t* Qr   = (bf16_t*)carve(T * 4096 * 2);
  bf16_t* Kr   = (bf16_t*)carve(T * 1024 * 2);
  bf16_t* Vr   = (bf16_t*)carve(T * 1024 * 2);
  bf16_t* Obf  = (bf16_t*)carve(T * 4096 * 2);

  cvt_bf16<<<2048, 256, 0, stream>>>(X, Xbf, (int)(T * 4096 / 4));
  transpose_cvt<<<dim3(64, 64), 256, 0, stream>>>(Wq, WqT, 4096, 4096);
  transpose_cvt<<<dim3(16, 64), 256, 0, stream>>>(Wk, WkT, 4096, 1024);
  transpose_cvt<<<dim3(16, 64), 256, 0, stream>>>(Wv, WvT, 4096, 1024);
  transpose_cvt<<<dim3(64, 64), 256, 0, stream>>>(Wo, WoT, 4096, 4096);

  gemm_bf16<1><<<dim3(32, 32), 256, 0, stream>>>(Xbf, WqT, Qraw, 4096, 4096, 4096);
  gemm_bf16<1><<<dim3(8, 32), 256, 0, stream>>>(Xbf, WkT, Kraw, 4096, 1024, 4096);
  gemm_bf16<1><<<dim3(8, 32), 256, 0, stream>>>(Xbf, WvT, Vraw, 4096, 1024, 4096);

  rope_pack<<<(int)(T * 48 / 4), 256, 0, stream>>>(Qraw, Kraw, Vraw, pos, Qr, Kr, Vr);

  attn_kernel<<<dim3(128, 64), 64, 0, stream>>>(Qr, Kr, Vr, Obf);

  gemm_bf16<0><<<dim3(32, 32), 256, 0, stream>>>(Obf, WoT, out, 4096, 4096, 4096);
}

// Round 2
// 1033.878 us; speedup vs baseline: 1.3922x; 1.3922x over previous
//
#include <hip/hip_runtime.h>
#include <hip/hip_bf16.h>

typedef __bf16 bf16_t;
typedef float  f32x4  __attribute__((ext_vector_type(4)));
typedef bf16_t bf16x4 __attribute__((ext_vector_type(4)));
typedef bf16_t bf16x8 __attribute__((ext_vector_type(8)));

#define MFMA16(a, b, c) __builtin_amdgcn_mfma_f32_16x16x32_bf16((a), (b), (c), 0, 0, 0)

#define GLOAD_LDS16(g, l)                                                              \
  __builtin_amdgcn_global_load_lds((const __attribute__((address_space(1))) void*)(g), \
                                   (__attribute__((address_space(3))) void*)(l), 16, 0, 0)

// ---------------- elementwise f32 -> bf16 ----------------
__global__ __launch_bounds__(256) void cvt_bf16(const float* __restrict__ in,
                                                bf16_t* __restrict__ out, int n4) {
  int stride = gridDim.x * blockDim.x;
  for (int i = blockIdx.x * blockDim.x + threadIdx.x; i < n4; i += stride) {
    f32x4 v = ((const f32x4*)in)[i];
    bf16x4 o;
#pragma unroll
    for (int j = 0; j < 4; ++j) o[j] = (bf16_t)v[j];
    ((bf16x4*)out)[i] = o;
  }
}

// ---------------- transpose + convert: in[R][C] f32 -> out[C][R] bf16 ----------------
__global__ __launch_bounds__(256) void transpose_cvt(const float* __restrict__ in,
                                                     bf16_t* __restrict__ out,
                                                     int R, int C) {
  __shared__ float t[64][65];
  int tr0 = blockIdx.y * 64, tc0 = blockIdx.x * 64;
  int tx = threadIdx.x & 15, ty = threadIdx.x >> 4;
#pragma unroll
  for (int i = 0; i < 4; ++i) {
    f32x4 v = *(const f32x4*)(in + (size_t)(tr0 + ty + 16 * i) * C + tc0 + tx * 4);
#pragma unroll
    for (int j = 0; j < 4; ++j) t[ty + 16 * i][tx * 4 + j] = v[j];
  }
  __syncthreads();
#pragma unroll
  for (int i = 0; i < 4; ++i) {
    bf16x4 o4;
#pragma unroll
    for (int j = 0; j < 4; ++j) o4[j] = (bf16_t)t[tx * 4 + j][ty + 16 * i];
    *(bf16x4*)(out + (size_t)(tc0 + ty + 16 * i) * R + tr0 + tx * 4) = o4;
  }
}

// ---------------- GEMM (m97 structure): C[M][N] = A[M][K] * Bt[N][K]^T ----------------
template <int WRITE_BF16>
__global__ __launch_bounds__(256) void gemm_bf16(const bf16_t* __restrict__ A,
                                                 const bf16_t* __restrict__ Bt,
                                                 void* __restrict__ Cv,
                                                 int M, int N, int K) {
  __shared__ alignas(16) bf16_t Al[128 * 64];
  __shared__ alignas(16) bf16_t Bl[128 * 64];
  const int tid = threadIdx.x;
  const int lane = tid & 63, w = tid >> 6;
  const int wr = w >> 1, wc = w & 1;
  const int g = lane >> 4, ci = lane & 15;
  const int m0 = blockIdx.y * 128, n0 = blockIdx.x * 128;

  f32x4 acc[4][4];
#pragma unroll
  for (int m = 0; m < 4; ++m)
#pragma unroll
    for (int n = 0; n < 4; ++n) acc[m][n] = f32x4{0.f, 0.f, 0.f, 0.f};

  for (int kt = 0; kt < K; kt += 64) {
    __syncthreads();
#pragma unroll
    for (int j = 0; j < 4; ++j) {
      int e = (w * 4 + j) * 512 + lane * 8;  // element idx in 128x64 tile
      int row = e >> 6, kc = e & 63;
      GLOAD_LDS16(A + (size_t)(m0 + row) * K + kt + kc, (char*)Al + (w * 4 + j) * 1024);
      GLOAD_LDS16(Bt + (size_t)(n0 + row) * K + kt + kc, (char*)Bl + (w * 4 + j) * 1024);
    }
    __syncthreads();
#pragma unroll
    for (int ks = 0; ks < 2; ++ks) {
      bf16x8 af[4], bv[4];
#pragma unroll
      for (int m = 0; m < 4; ++m)
        af[m] = *(const bf16x8*)&Al[(wr * 64 + m * 16 + ci) * 64 + ks * 32 + g * 8];
#pragma unroll
      for (int n = 0; n < 4; ++n)
        bv[n] = *(const bf16x8*)&Bl[(wc * 64 + n * 16 + ci) * 64 + ks * 32 + g * 8];
#pragma unroll
      for (int m = 0; m < 4; ++m)
#pragma unroll
        for (int n = 0; n < 4; ++n) acc[m][n] = MFMA16(af[m], bv[n], acc[m][n]);
    }
  }
  // epilogue: D row = (l>>4)*4 + r, col = l&15 (verified layout)
#pragma unroll
  for (int m = 0; m < 4; ++m) {
#pragma unroll
    for (int n = 0; n < 4; ++n) {
      int grow = m0 + wr * 64 + m * 16 + g * 4;
      int gcol = n0 + wc * 64 + n * 16 + ci;
#pragma unroll
      for (int r = 0; r < 4; ++r) {
        if (WRITE_BF16)
          ((bf16_t*)Cv)[(size_t)(grow + r) * N + gcol] = (bf16_t)acc[m][n][r];
        else
          ((float*)Cv)[(size_t)(grow + r) * N + gcol] = acc[m][n][r];
      }
    }
  }
}

// ---------------- RoPE + repack to [B,H,N,D] ----------------
__global__ __launch_bounds__(256) void rope_pack(const bf16_t* __restrict__ Qraw,
                                                 const bf16_t* __restrict__ Kraw,
                                                 const bf16_t* __restrict__ Vraw,
                                                 const int* __restrict__ pos,
                                                 bf16_t* __restrict__ Qr,
                                                 bf16_t* __restrict__ Kr,
                                                 bf16_t* __restrict__ Vr) {
  int unit = blockIdx.x * 4 + (threadIdx.x >> 6);
  int lane = threadIdx.x & 63;
  int token = unit / 48, slot = unit % 48;
  int b = token >> 11, n = token & 2047;
  if (slot < 40) {
    float p = (float)pos[token];
    float inv = powf(10000.0f, -(float)lane * (1.0f / 64.0f));
    float ang = p * inv;
    float cs = cosf(ang), sn = sinf(ang);
    const bf16_t* src;
    bf16_t* dst;
    if (slot < 32) {
      src = Qraw + (size_t)token * 4096 + slot * 128;
      dst = Qr + ((size_t)(b * 32 + slot) * 2048 + n) * 128;
    } else {
      int kvh = slot - 32;
      src = Kraw + (size_t)token * 1024 + kvh * 128;
      dst = Kr + ((size_t)(b * 8 + kvh) * 2048 + n) * 128;
    }
    float x0 = (float)src[lane], x1 = (float)src[lane + 64];
    dst[lane] = (bf16_t)(x0 * cs - x1 * sn);
    dst[lane + 64] = (bf16_t)(x1 * cs + x0 * sn);
  } else {
    int kvh = slot - 40;
    const bf16_t* src = Vraw + (size_t)token * 1024 + kvh * 128;
    bf16_t* dst = Vr + ((size_t)(b * 8 + kvh) * 2048 + n) * 128;
    dst[lane] = src[lane];
    dst[lane + 64] = src[lane + 64];
  }
}

// ---------------- flash attention: 4 waves/block, 128 q-rows, KVBLK=64 ----------------
// S^T = mfma(A=K, B=Q): softmax axis kv is lane-local x 4 g-groups.
__global__ __launch_bounds__(256) void attn_kernel(const bf16_t* __restrict__ Q,
                                                   const bf16_t* __restrict__ K,
                                                   const bf16_t* __restrict__ V,
                                                   bf16_t* __restrict__ O) {
  const float scale = 0.08838834764831845f;  // 1/sqrt(128)
  __shared__ alignas(16) bf16_t Kl[64 * 128];   // swizzled [kv][d]
  __shared__ alignas(16) bf16_t Vt[128 * 64];   // swizzled [d][kv]
  __shared__ alignas(16) bf16_t Pl[4][32 * 64]; // per-wave swizzled [q][kv]
  const int tid = threadIdx.x;
  const int lane = tid & 63, w = tid >> 6;
  const int g = lane >> 4, ci = lane & 15;
  const int hb = blockIdx.y;  // b*32 + h
  const int b = hb >> 5, h = hb & 31, kvh = h >> 2;
  const int qt = gridDim.x - 1 - blockIdx.x;  // reversed: longest blocks first
  const int qr0 = qt * 128 + w * 32;
  const bf16_t* Qh = Q + (size_t)hb * 2048 * 128;
  const bf16_t* Kh = K + (size_t)(b * 8 + kvh) * 2048 * 128;
  const bf16_t* Vh = V + (size_t)(b * 8 + kvh) * 2048 * 128;

  // Q fragments (B operand of S^T): col = q = ci
  bf16x8 bq[2][4];
#pragma unroll
  for (int qb = 0; qb < 2; ++qb)
#pragma unroll
    for (int ks = 0; ks < 4; ++ks)
      bq[qb][ks] = *(const bf16x8*)(Qh + (size_t)(qr0 + qb * 16 + ci) * 128 + ks * 32 + g * 8);

  f32x4 o[2][8];
#pragma unroll
  for (int qb = 0; qb < 2; ++qb)
#pragma unroll
    for (int nb = 0; nb < 8; ++nb) o[qb][nb] = f32x4{0.f, 0.f, 0.f, 0.f};
  float mrow[2] = {-1e30f, -1e30f};
  float lrow[2] = {0.f, 0.f};

  const int nt = (qt + 1) * 2;
  for (int t = 0; t < nt; ++t) {
    const int kv0 = t * 64;
    __syncthreads();
    // ---- stage K [64][128] (swizzled rows) ----
#pragma unroll
    for (int i = 0; i < 4; ++i) {
      int c = tid + i * 256;
      int row = c >> 4, kc = (c & 15) * 8;
      bf16x8 kx = *(const bf16x8*)(Kh + (size_t)(kv0 + row) * 128 + kc);
      int sw = ((row ^ (row >> 3)) & 7) << 4;
      *(bf16x8*)((char*)Kl + row * 256 + ((kc * 2) ^ sw)) = kx;
    }
    // ---- stage V transposed -> Vt[d][kv] (swizzled rows) ----
    {
      int kq = tid >> 5, dq = tid & 31;
      bf16x4 rv[8];
#pragma unroll
      for (int rr = 0; rr < 8; ++rr)
        rv[rr] = *(const bf16x4*)(Vh + (size_t)(kv0 + kq * 8 + rr) * 128 + dq * 4);
#pragma unroll
      for (int jj = 0; jj < 4; ++jj) {
        int d = dq * 4 + jj;
        bf16x8 cv;
#pragma unroll
        for (int rr = 0; rr < 8; ++rr) cv[rr] = rv[rr][jj];
        int sw = ((d ^ (d >> 3)) & 7) << 4;
        *(bf16x8*)((char*)Vt + d * 128 + ((kq * 16) ^ sw)) = cv;
      }
    }
    __syncthreads();

    if (kv0 <= qr0 + 31) {  // wave has at least one unmasked row in this tile
      // ---- QK^T (transposed): st[qb][kvb], D row = kv-local 4g+r, col = q-local ci ----
      f32x4 st[2][4];
#pragma unroll
      for (int qb = 0; qb < 2; ++qb)
#pragma unroll
        for (int kvb = 0; kvb < 4; ++kvb) st[qb][kvb] = f32x4{0.f, 0.f, 0.f, 0.f};
#pragma unroll
      for (int kvb = 0; kvb < 4; ++kvb) {
        int row = kvb * 16 + ci;
        int sw = ((row ^ (row >> 3)) & 7) << 4;
        bf16x8 ak[4];
#pragma unroll
        for (int ks = 0; ks < 4; ++ks)
          ak[ks] = *(const bf16x8*)((char*)Kl + row * 256 + ((ks * 64 + g * 16) ^ sw));
#pragma unroll
        for (int qb = 0; qb < 2; ++qb)
#pragma unroll
          for (int ks = 0; ks < 4; ++ks)
            st[qb][kvb] = MFMA16(ak[ks], bq[qb][ks], st[qb][kvb]);
      }
      const bool needmask = (kv0 + 63 > qr0);
      // ---- online softmax (per q = ci), P -> Pl ----
#pragma unroll
      for (int qb = 0; qb < 2; ++qb) {
        int q = qr0 + qb * 16 + ci;
        float p[16];
        float pm = -1e30f;
#pragma unroll
        for (int kvb = 0; kvb < 4; ++kvb)
#pragma unroll
          for (int r = 0; r < 4; ++r) {
            float v = st[qb][kvb][r] * scale;
            if (needmask && (kv0 + kvb * 16 + 4 * g + r > q)) v = -1e30f;
            p[kvb * 4 + r] = v;
            pm = fmaxf(pm, v);
          }
        pm = fmaxf(pm, __shfl_xor(pm, 16));
        pm = fmaxf(pm, __shfl_xor(pm, 32));
        float mnew = fmaxf(mrow[qb], pm);
        float fs = __expf(mrow[qb] - mnew);
        mrow[qb] = mnew;
        float ps = 0.f;
#pragma unroll
        for (int e = 0; e < 16; ++e) {
          p[e] = __expf(p[e] - mnew);
          ps += p[e];
        }
        ps += __shfl_xor(ps, 16);
        ps += __shfl_xor(ps, 32);
        lrow[qb] = lrow[qb] * fs + ps;
        int prow = qb * 16 + ci;
        int sw = ((prow ^ (prow >> 3)) & 7) << 4;
#pragma unroll
        for (int kvb = 0; kvb < 4; ++kvb) {
          bf16x4 pk;
#pragma unroll
          for (int r = 0; r < 4; ++r) pk[r] = (bf16_t)p[kvb * 4 + r];
          *(bf16x4*)((char*)&Pl[w][0] + prow * 128 + (((kvb * 16 + 4 * g) * 2) ^ sw)) = pk;
        }
        // rescale o (O layout: q-local row = 4g+r -> fs from lane 4g+r)
        float fo[4];
#pragma unroll
        for (int r = 0; r < 4; ++r) fo[r] = __shfl(fs, 4 * g + r);
#pragma unroll
        for (int nb = 0; nb < 8; ++nb)
#pragma unroll
          for (int r = 0; r < 4; ++r) o[qb][nb][r] *= fo[r];
      }
      // ---- PV: O[q][d] += P[q][kv] Vt[d][kv] ----
      bf16x8 pa[2][2];
#pragma unroll
      for (int qb = 0; qb < 2; ++qb) {
        int prow = qb * 16 + ci;
        int sw = ((prow ^ (prow >> 3)) & 7) << 4;
#pragma unroll
        for (int ks = 0; ks < 2; ++ks)
          pa[qb][ks] = *(const bf16x8*)((char*)&Pl[w][0] + prow * 128 + ((ks * 64 + g * 16) ^ sw));
      }
#pragma unroll
      for (int nb = 0; nb < 8; ++nb) {
        int d = nb * 16 + ci;
        int sw = ((d ^ (d >> 3)) & 7) << 4;
        bf16x8 bv0 = *(const bf16x8*)((char*)Vt + d * 128 + ((g * 16) ^ sw));
        bf16x8 bv1 = *(const bf16x8*)((char*)Vt + d * 128 + ((64 + g * 16) ^ sw));
#pragma unroll
        for (int qb = 0; qb < 2; ++qb) {
          o[qb][nb] = MFMA16(pa[qb][0], bv0, o[qb][nb]);
          o[qb][nb] = MFMA16(pa[qb][1], bv1, o[qb][nb]);
        }
      }
    }
  }
  // ---- epilogue ----
#pragma unroll
  for (int qb = 0; qb < 2; ++qb) {
    float linv = 1.0f / lrow[qb];
    float lv[4];
#pragma unroll
    for (int r = 0; r < 4; ++r) lv[r] = __shfl(linv, 4 * g + r);
#pragma unroll
    for (int r = 0; r < 4; ++r) {
      int n = qr0 + qb * 16 + 4 * g + r;
      bf16_t* op = O + (size_t)(b * 2048 + n) * 4096 + h * 128;
#pragma unroll
      for (int nb = 0; nb < 8; ++nb) op[nb * 16 + ci] = (bf16_t)(o[qb][nb][r] * lv[r]);
    }
  }
}

extern "C" void kernel_launch(void* const* d_in, const int* in_sizes, int n_in,
                              void* d_out, int out_size, void* d_ws, size_t ws_size,
                              hipStream_t stream) {
  (void)in_sizes; (void)n_in; (void)out_size; (void)ws_size;
  const float* X = (const float*)d_in[0];
  const int* pos = (const int*)d_in[1];
  const float* Wq = (const float*)d_in[2];
  const float* Wk = (const float*)d_in[3];
  const float* Wv = (const float*)d_in[4];
  const float* Wo = (const float*)d_in[5];
  float* out = (float*)d_out;

  char* w = (char*)d_ws;
  auto carve = [&](size_t bytes) {
    void* p = (void*)w;
    w += (bytes + 255) & ~(size_t)255;
    return p;
  };
  const size_t T = 4096;  // B*N tokens
  bf16_t* Xbf  = (bf16_t*)carve(T * 4096 * 2);
  bf16_t* WqT  = (bf16_t*)carve(4096ull * 4096 * 2);
  bf16_t* WkT  = (bf16_t*)carve(1024ull * 4096 * 2);
  bf16_t* WvT  = (bf16_t*)carve(1024ull * 4096 * 2);
  bf16_t* WoT  = (bf16_t*)carve(4096ull * 4096 * 2);
  bf16_t* Qraw = (bf16_t*)carve(T * 4096 * 2);
  bf16_t* Kraw = (bf16_t*)carve(T * 1024 * 2);
  bf16_t* Vraw = (bf16_t*)carve(T * 1024 * 2);
  bf16_t* Qr   = (bf16_t*)carve(T * 4096 * 2);
  bf16_t* Kr   = (bf16_t*)carve(T * 1024 * 2);
  bf16_t* Vr   = (bf16_t*)carve(T * 1024 * 2);
  bf16_t* Obf  = (bf16_t*)carve(T * 4096 * 2);

  cvt_bf16<<<2048, 256, 0, stream>>>(X, Xbf, (int)(T * 4096 / 4));
  transpose_cvt<<<dim3(64, 64), 256, 0, stream>>>(Wq, WqT, 4096, 4096);
  transpose_cvt<<<dim3(16, 64), 256, 0, stream>>>(Wk, WkT, 4096, 1024);
  transpose_cvt<<<dim3(16, 64), 256, 0, stream>>>(Wv, WvT, 4096, 1024);
  transpose_cvt<<<dim3(64, 64), 256, 0, stream>>>(Wo, WoT, 4096, 4096);

  gemm_bf16<1><<<dim3(32, 32), 256, 0, stream>>>(Xbf, WqT, Qraw, 4096, 4096, 4096);
  gemm_bf16<1><<<dim3(8, 32), 256, 0, stream>>>(Xbf, WkT, Kraw, 4096, 1024, 4096);
  gemm_bf16<1><<<dim3(8, 32), 256, 0, stream>>>(Xbf, WvT, Vraw, 4096, 1024, 4096);

  rope_pack<<<(int)(T * 48 / 4), 256, 0, stream>>>(Qraw, Kraw, Vraw, pos, Qr, Kr, Vr);

  attn_kernel<<<dim3(16, 64), 256, 0, stream>>>(Qr, Kr, Vr, Obf);

  gemm_bf16<0><<<dim3(32, 32), 256, 0, stream>>>(Obf, WoT, out, 4096, 4096, 4096);
}

// Round 3
// 776.533 us; speedup vs baseline: 1.8536x; 1.3314x over previous
//
#include <hip/hip_runtime.h>
#include <hip/hip_bf16.h>

typedef __bf16 bf16_t;
typedef float  f32x4  __attribute__((ext_vector_type(4)));
typedef bf16_t bf16x4 __attribute__((ext_vector_type(4)));
typedef bf16_t bf16x8 __attribute__((ext_vector_type(8)));

#define MFMA16(a, b, c) __builtin_amdgcn_mfma_f32_16x16x32_bf16((a), (b), (c), 0, 0, 0)

#define GLOAD_LDS16(g, l)                                                              \
  __builtin_amdgcn_global_load_lds((const __attribute__((address_space(1))) void*)(g), \
                                   (__attribute__((address_space(3))) void*)(l), 16, 0, 0)

// ---------------- elementwise f32 -> bf16 ----------------
__global__ __launch_bounds__(256) void cvt_bf16(const float* __restrict__ in,
                                                bf16_t* __restrict__ out, int n4) {
  int stride = gridDim.x * blockDim.x;
  for (int i = blockIdx.x * blockDim.x + threadIdx.x; i < n4; i += stride) {
    f32x4 v = ((const f32x4*)in)[i];
    bf16x4 o;
#pragma unroll
    for (int j = 0; j < 4; ++j) o[j] = (bf16_t)v[j];
    ((bf16x4*)out)[i] = o;
  }
}

// ---------------- transpose + convert: in[R][C] f32 -> out[C][R] bf16 ----------------
__global__ __launch_bounds__(256) void transpose_cvt(const float* __restrict__ in,
                                                     bf16_t* __restrict__ out,
                                                     int R, int C) {
  __shared__ float t[64][65];
  int tr0 = blockIdx.y * 64, tc0 = blockIdx.x * 64;
  int tx = threadIdx.x & 15, ty = threadIdx.x >> 4;
#pragma unroll
  for (int i = 0; i < 4; ++i) {
    f32x4 v = *(const f32x4*)(in + (size_t)(tr0 + ty + 16 * i) * C + tc0 + tx * 4);
#pragma unroll
    for (int j = 0; j < 4; ++j) t[ty + 16 * i][tx * 4 + j] = v[j];
  }
  __syncthreads();
#pragma unroll
  for (int i = 0; i < 4; ++i) {
    bf16x4 o4;
#pragma unroll
    for (int j = 0; j < 4; ++j) o4[j] = (bf16_t)t[tx * 4 + j][ty + 16 * i];
    *(bf16x4*)(out + (size_t)(tc0 + ty + 16 * i) * R + tr0 + tx * 4) = o4;
  }
}

// ---------------- GEMM (m97 structure): C[M][N] = A[M][K] * Bt[N][K]^T ----------------
template <int WRITE_BF16>
__global__ __launch_bounds__(256) void gemm_bf16(const bf16_t* __restrict__ A,
                                                 const bf16_t* __restrict__ Bt,
                                                 void* __restrict__ Cv,
                                                 int M, int N, int K) {
  __shared__ alignas(16) bf16_t Al[128 * 64];
  __shared__ alignas(16) bf16_t Bl[128 * 64];
  const int tid = threadIdx.x;
  const int lane = tid & 63, w = tid >> 6;
  const int wr = w >> 1, wc = w & 1;
  const int g = lane >> 4, ci = lane & 15;
  const int m0 = blockIdx.y * 128, n0 = blockIdx.x * 128;

  f32x4 acc[4][4];
#pragma unroll
  for (int m = 0; m < 4; ++m)
#pragma unroll
    for (int n = 0; n < 4; ++n) acc[m][n] = f32x4{0.f, 0.f, 0.f, 0.f};

  for (int kt = 0; kt < K; kt += 64) {
    __syncthreads();
#pragma unroll
    for (int j = 0; j < 4; ++j) {
      int e = (w * 4 + j) * 512 + lane * 8;  // element idx in 128x64 tile
      int row = e >> 6, kc = e & 63;
      GLOAD_LDS16(A + (size_t)(m0 + row) * K + kt + kc, (char*)Al + (w * 4 + j) * 1024);
      GLOAD_LDS16(Bt + (size_t)(n0 + row) * K + kt + kc, (char*)Bl + (w * 4 + j) * 1024);
    }
    __syncthreads();
#pragma unroll
    for (int ks = 0; ks < 2; ++ks) {
      bf16x8 af[4], bv[4];
#pragma unroll
      for (int m = 0; m < 4; ++m)
        af[m] = *(const bf16x8*)&Al[(wr * 64 + m * 16 + ci) * 64 + ks * 32 + g * 8];
#pragma unroll
      for (int n = 0; n < 4; ++n)
        bv[n] = *(const bf16x8*)&Bl[(wc * 64 + n * 16 + ci) * 64 + ks * 32 + g * 8];
#pragma unroll
      for (int m = 0; m < 4; ++m)
#pragma unroll
        for (int n = 0; n < 4; ++n) acc[m][n] = MFMA16(af[m], bv[n], acc[m][n]);
    }
  }
  // epilogue: D row = (l>>4)*4 + r, col = l&15 (verified layout)
#pragma unroll
  for (int m = 0; m < 4; ++m) {
#pragma unroll
    for (int n = 0; n < 4; ++n) {
      int grow = m0 + wr * 64 + m * 16 + g * 4;
      int gcol = n0 + wc * 64 + n * 16 + ci;
#pragma unroll
      for (int r = 0; r < 4; ++r) {
        if (WRITE_BF16)
          ((bf16_t*)Cv)[(size_t)(grow + r) * N + gcol] = (bf16_t)acc[m][n][r];
        else
          ((float*)Cv)[(size_t)(grow + r) * N + gcol] = acc[m][n][r];
      }
    }
  }
}

// ---------------- RoPE + repack: fused QKV [token][6144] -> per-head [B,H,N,D] ----------------
__global__ __launch_bounds__(256) void rope_pack(const bf16_t* __restrict__ QKV,
                                                 const int* __restrict__ pos,
                                                 bf16_t* __restrict__ Qr,
                                                 bf16_t* __restrict__ Kr,
                                                 bf16_t* __restrict__ Vr) {
  int unit = blockIdx.x * 4 + (threadIdx.x >> 6);
  int lane = threadIdx.x & 63;
  int token = unit / 48, slot = unit % 48;
  int b = token >> 11, n = token & 2047;
  const bf16_t* base = QKV + (size_t)token * 6144;
  if (slot < 40) {
    float p = (float)pos[token];
    // inv_freq = 10000^(-lane/64) = exp2(-lane * log2(10000)/64)
    float inv = exp2f(-(float)lane * 0.20762050593045702f);
    float ang = p * inv;
    float sn, cs;
    sincosf(ang, &sn, &cs);
    const bf16_t* src;
    bf16_t* dst;
    if (slot < 32) {
      src = base + slot * 128;
      dst = Qr + ((size_t)(b * 32 + slot) * 2048 + n) * 128;
    } else {
      int kvh = slot - 32;
      src = base + 4096 + kvh * 128;
      dst = Kr + ((size_t)(b * 8 + kvh) * 2048 + n) * 128;
    }
    float x0 = (float)src[lane], x1 = (float)src[lane + 64];
    dst[lane] = (bf16_t)(x0 * cs - x1 * sn);
    dst[lane + 64] = (bf16_t)(x1 * cs + x0 * sn);
  } else {
    int kvh = slot - 40;
    const bf16_t* src = base + 5120 + kvh * 128;
    bf16_t* dst = Vr + ((size_t)(b * 8 + kvh) * 2048 + n) * 128;
    dst[lane] = src[lane];
    dst[lane + 64] = src[lane + 64];
  }
}

// ---------------- flash attention: 8 waves/block, paired q-tiles (balanced causal) ----
// Block (p, hb): waves own 16 rows of q-tile p ("A", qb=0) + 16 rows of tile 15-p ("B", qb=1).
// Work per block = 2(p+1) + 2(16-p) = 34 tile-halves: grid-uniform.
// S^T = mfma(A=K, B=Q): softmax axis kv is lane-local x 4 g-groups.
__global__ __launch_bounds__(512) void attn_kernel(const bf16_t* __restrict__ Q,
                                                   const bf16_t* __restrict__ K,
                                                   const bf16_t* __restrict__ V,
                                                   bf16_t* __restrict__ O) {
  const float scale = 0.08838834764831845f;  // 1/sqrt(128)
  __shared__ alignas(16) bf16_t Kl[64 * 128];    // swizzled [kv][d]
  __shared__ alignas(16) bf16_t Vt[128 * 64];    // swizzled [d][kv]
  __shared__ alignas(16) bf16_t Pl[8][32 * 64];  // per-wave swizzled [q][kv]
  const int tid = threadIdx.x;
  const int lane = tid & 63, w = tid >> 6;
  const int g = lane >> 4, ci = lane & 15;
  const int hb = blockIdx.y;  // b*32 + h
  const int b = hb >> 5, h = hb & 31, kvh = h >> 2;
  const int p = blockIdx.x;  // pair index 0..7
  const int qtB = 15 - p;
  const int qr[2] = {p * 128 + w * 16, qtB * 128 + w * 16};
  const bf16_t* Qh = Q + (size_t)hb * 2048 * 128;
  const bf16_t* Kh = K + (size_t)(b * 8 + kvh) * 2048 * 128;
  const bf16_t* Vh = V + (size_t)(b * 8 + kvh) * 2048 * 128;

  // Q fragments (B operand of S^T): col = q = ci
  bf16x8 bq[2][4];
#pragma unroll
  for (int qb = 0; qb < 2; ++qb)
#pragma unroll
    for (int ks = 0; ks < 4; ++ks)
      bq[qb][ks] = *(const bf16x8*)(Qh + (size_t)(qr[qb] + ci) * 128 + ks * 32 + g * 8);

  f32x4 o[2][8];
#pragma unroll
  for (int qb = 0; qb < 2; ++qb)
#pragma unroll
    for (int nb = 0; nb < 8; ++nb) o[qb][nb] = f32x4{0.f, 0.f, 0.f, 0.f};
  float mrow[2] = {-1e30f, -1e30f};
  float lrow[2] = {0.f, 0.f};

  const int nt = (qtB + 1) * 2;
  for (int t = 0; t < nt; ++t) {
    const int kv0 = t * 64;
    __syncthreads();
    // ---- stage K [64][128] (swizzled rows), 512 threads ----
#pragma unroll
    for (int i = 0; i < 2; ++i) {
      int c = tid + i * 512;
      int row = c >> 4, kc = (c & 15) * 8;
      bf16x8 kx = *(const bf16x8*)(Kh + (size_t)(kv0 + row) * 128 + kc);
      int sw = ((row ^ (row >> 3)) & 7) << 4;
      *(bf16x8*)((char*)Kl + row * 256 + ((kc * 2) ^ sw)) = kx;
    }
    // ---- stage V transposed -> Vt[d][kv] (swizzled rows), 512 threads ----
    {
      int kq = tid >> 5, dq = tid & 31;  // kq 0..15 (4 kv rows each), dq 0..31 (4 d each)
      bf16x4 rv[4];
#pragma unroll
      for (int rr = 0; rr < 4; ++rr)
        rv[rr] = *(const bf16x4*)(Vh + (size_t)(kv0 + kq * 4 + rr) * 128 + dq * 4);
#pragma unroll
      for (int jj = 0; jj < 4; ++jj) {
        int d = dq * 4 + jj;
        bf16x4 cv;
#pragma unroll
        for (int rr = 0; rr < 4; ++rr) cv[rr] = rv[rr][jj];
        int sw = ((d ^ (d >> 3)) & 7) << 4;
        *(bf16x4*)((char*)Vt + d * 128 + ((kq * 8) ^ sw)) = cv;
      }
    }
    __syncthreads();

    bool act[2] = {kv0 <= qr[0] + 15, kv0 <= qr[1] + 15};
#pragma unroll
    for (int qb = 0; qb < 2; ++qb) {
      if (!act[qb]) continue;  // no barriers inside: per-wave divergence safe
      // ---- QK^T (transposed): st[kvb], D row = kv-local 4g+r, col = q-local ci ----
      f32x4 st[4];
#pragma unroll
      for (int kvb = 0; kvb < 4; ++kvb) st[kvb] = f32x4{0.f, 0.f, 0.f, 0.f};
      __builtin_amdgcn_s_setprio(1);
#pragma unroll
      for (int kvb = 0; kvb < 4; ++kvb) {
        int row = kvb * 16 + ci;
        int sw = ((row ^ (row >> 3)) & 7) << 4;
#pragma unroll
        for (int ks = 0; ks < 4; ++ks) {
          bf16x8 ak = *(const bf16x8*)((char*)Kl + row * 256 + ((ks * 64 + g * 16) ^ sw));
          st[kvb] = MFMA16(ak, bq[qb][ks], st[kvb]);
        }
      }
      __builtin_amdgcn_s_setprio(0);
      // ---- online softmax (per q = ci) ----
      const int q = qr[qb] + ci;
      const bool needmask = (kv0 + 63 > qr[qb]);
      float pv[16];
      float pm = -1e30f;
#pragma unroll
      for (int kvb = 0; kvb < 4; ++kvb)
#pragma unroll
        for (int r = 0; r < 4; ++r) {
          float v = st[kvb][r] * scale;
          if (needmask && (kv0 + kvb * 16 + 4 * g + r > q)) v = -1e30f;
          pv[kvb * 4 + r] = v;
          pm = fmaxf(pm, v);
        }
      pm = fmaxf(pm, __shfl_xor(pm, 16));
      pm = fmaxf(pm, __shfl_xor(pm, 32));
      float mnew = fmaxf(mrow[qb], pm);
      float fs = __expf(mrow[qb] - mnew);
      mrow[qb] = mnew;
      float ps = 0.f;
#pragma unroll
      for (int e = 0; e < 16; ++e) {
        pv[e] = __expf(pv[e] - mnew);
        ps += pv[e];
      }
      ps += __shfl_xor(ps, 16);
      ps += __shfl_xor(ps, 32);
      lrow[qb] = lrow[qb] * fs + ps;
      // P -> Pl (swizzled)
      int prow = qb * 16 + ci;
      int swp = ((prow ^ (prow >> 3)) & 7) << 4;
#pragma unroll
      for (int kvb = 0; kvb < 4; ++kvb) {
        bf16x4 pk;
#pragma unroll
        for (int r = 0; r < 4; ++r) pk[r] = (bf16_t)pv[kvb * 4 + r];
        *(bf16x4*)((char*)&Pl[w][0] + prow * 128 + (((kvb * 16 + 4 * g) * 2) ^ swp)) = pk;
      }
      // rescale o (O layout: q-local row = 4g+r -> fs from lane 4g+r; fs is g-uniform)
      float fo[4];
#pragma unroll
      for (int r = 0; r < 4; ++r) fo[r] = __shfl(fs, 4 * g + r);
#pragma unroll
      for (int nb = 0; nb < 8; ++nb)
#pragma unroll
        for (int r = 0; r < 4; ++r) o[qb][nb][r] *= fo[r];
    }
    // ---- PV: O[q][d] += P[q][kv] Vt[d][kv] ----
    bf16x8 pa[2][2];
#pragma unroll
    for (int qb = 0; qb < 2; ++qb) {
      if (!act[qb]) continue;
      int prow = qb * 16 + ci;
      int swp = ((prow ^ (prow >> 3)) & 7) << 4;
#pragma unroll
      for (int ks = 0; ks < 2; ++ks)
        pa[qb][ks] = *(const bf16x8*)((char*)&Pl[w][0] + prow * 128 + ((ks * 64 + g * 16) ^ swp));
    }
    __builtin_amdgcn_s_setprio(1);
#pragma unroll
    for (int nb = 0; nb < 8; ++nb) {
      int d = nb * 16 + ci;
      int sw = ((d ^ (d >> 3)) & 7) << 4;
      bf16x8 bv0 = *(const bf16x8*)((char*)Vt + d * 128 + ((g * 16) ^ sw));
      bf16x8 bv1 = *(const bf16x8*)((char*)Vt + d * 128 + ((64 + g * 16) ^ sw));
#pragma unroll
      for (int qb = 0; qb < 2; ++qb) {
        if (!act[qb]) continue;
        o[qb][nb] = MFMA16(pa[qb][0], bv0, o[qb][nb]);
        o[qb][nb] = MFMA16(pa[qb][1], bv1, o[qb][nb]);
      }
    }
    __builtin_amdgcn_s_setprio(0);
  }
  // ---- epilogue ----
#pragma unroll
  for (int qb = 0; qb < 2; ++qb) {
    float linv = 1.0f / lrow[qb];
    float lv[4];
#pragma unroll
    for (int r = 0; r < 4; ++r) lv[r] = __shfl(linv, 4 * g + r);
#pragma unroll
    for (int r = 0; r < 4; ++r) {
      int n = qr[qb] + 4 * g + r;
      bf16_t* op = O + (size_t)(b * 2048 + n) * 4096 + h * 128;
#pragma unroll
      for (int nb = 0; nb < 8; ++nb) op[nb * 16 + ci] = (bf16_t)(o[qb][nb][r] * lv[r]);
    }
  }
}

extern "C" void kernel_launch(void* const* d_in, const int* in_sizes, int n_in,
                              void* d_out, int out_size, void* d_ws, size_t ws_size,
                              hipStream_t stream) {
  (void)in_sizes; (void)n_in; (void)out_size; (void)ws_size;
  const float* X = (const float*)d_in[0];
  const int* pos = (const int*)d_in[1];
  const float* Wq = (const float*)d_in[2];
  const float* Wk = (const float*)d_in[3];
  const float* Wv = (const float*)d_in[4];
  const float* Wo = (const float*)d_in[5];
  float* out = (float*)d_out;

  char* w = (char*)d_ws;
  auto carve = [&](size_t bytes) {
    void* p = (void*)w;
    w += (bytes + 255) & ~(size_t)255;
    return p;
  };
  const size_t T = 4096;  // B*N tokens
  bf16_t* Xbf    = (bf16_t*)carve(T * 4096 * 2);
  bf16_t* WqkvT  = (bf16_t*)carve(6144ull * 4096 * 2);  // [Wq;Wk;Wv] transposed
  bf16_t* WoT    = (bf16_t*)carve(4096ull * 4096 * 2);
  bf16_t* QKVraw = (bf16_t*)carve(T * 6144 * 2);
  bf16_t* Qr     = (bf16_t*)carve(T * 4096 * 2);
  bf16_t* Kr     = (bf16_t*)carve(T * 1024 * 2);
  bf16_t* Vr     = (bf16_t*)carve(T * 1024 * 2);
  bf16_t* Obf    = (bf16_t*)carve(T * 4096 * 2);

  cvt_bf16<<<2048, 256, 0, stream>>>(X, Xbf, (int)(T * 4096 / 4));
  transpose_cvt<<<dim3(64, 64), 256, 0, stream>>>(Wq, WqkvT, 4096, 4096);
  transpose_cvt<<<dim3(16, 64), 256, 0, stream>>>(Wk, WqkvT + 4096ull * 4096, 4096, 1024);
  transpose_cvt<<<dim3(16, 64), 256, 0, stream>>>(Wv, WqkvT + 5120ull * 4096, 4096, 1024);
  transpose_cvt<<<dim3(64, 64), 256, 0, stream>>>(Wo, WoT, 4096, 4096);

  // fused QKV projection: [4096 tokens][6144]
  gemm_bf16<1><<<dim3(48, 32), 256, 0, stream>>>(Xbf, WqkvT, QKVraw, 4096, 6144, 4096);

  rope_pack<<<(int)(T * 48 / 4), 256, 0, stream>>>(QKVraw, pos, Qr, Kr, Vr);

  attn_kernel<<<dim3(8, 64), 512, 0, stream>>>(Qr, Kr, Vr, Obf);

  gemm_bf16<0><<<dim3(32, 32), 256, 0, stream>>>(Obf, WoT, out, 4096, 4096, 4096);
}

// Round 4
// 589.934 us; speedup vs baseline: 2.4399x; 1.3163x over previous
//
#include <hip/hip_runtime.h>
#include <hip/hip_bf16.h>

typedef __bf16 bf16_t;
typedef float  f32x4  __attribute__((ext_vector_type(4)));
typedef bf16_t bf16x4 __attribute__((ext_vector_type(4)));
typedef bf16_t bf16x8 __attribute__((ext_vector_type(8)));

#define MFMA16(a, b, c) __builtin_amdgcn_mfma_f32_16x16x32_bf16((a), (b), (c), 0, 0, 0)

#define GLOAD_LDS16(g, l)                                                              \
  __builtin_amdgcn_global_load_lds((const __attribute__((address_space(1))) void*)(g), \
                                   (__attribute__((address_space(3))) void*)(l), 16, 0, 0)

#define BARRIER    __builtin_amdgcn_s_barrier()
#define WAIT_LGKM0 asm volatile("s_waitcnt lgkmcnt(0)" ::: "memory")
#define WAIT_VM4   asm volatile("s_waitcnt vmcnt(4)" ::: "memory")
#define WAIT_VM6   asm volatile("s_waitcnt vmcnt(6)" ::: "memory")
#define WAIT_VM0   asm volatile("s_waitcnt vmcnt(0)" ::: "memory")

// ---------------- elementwise f32 -> bf16 ----------------
__global__ __launch_bounds__(256) void cvt_bf16(const float* __restrict__ in,
                                                bf16_t* __restrict__ out, int n4) {
  int stride = gridDim.x * blockDim.x;
  for (int i = blockIdx.x * blockDim.x + threadIdx.x; i < n4; i += stride) {
    f32x4 v = ((const f32x4*)in)[i];
    bf16x4 o;
#pragma unroll
    for (int j = 0; j < 4; ++j) o[j] = (bf16_t)v[j];
    ((bf16x4*)out)[i] = o;
  }
}

// ---------------- transpose + convert: in[R][C] f32 -> out[C][R] bf16 ----------------
__global__ __launch_bounds__(256) void transpose_cvt(const float* __restrict__ in,
                                                     bf16_t* __restrict__ out,
                                                     int R, int C) {
  __shared__ float t[64][65];
  int tr0 = blockIdx.y * 64, tc0 = blockIdx.x * 64;
  int tx = threadIdx.x & 15, ty = threadIdx.x >> 4;
#pragma unroll
  for (int i = 0; i < 4; ++i) {
    f32x4 v = *(const f32x4*)(in + (size_t)(tr0 + ty + 16 * i) * C + tc0 + tx * 4);
#pragma unroll
    for (int j = 0; j < 4; ++j) t[ty + 16 * i][tx * 4 + j] = v[j];
  }
  __syncthreads();
#pragma unroll
  for (int i = 0; i < 4; ++i) {
    bf16x4 o4;
#pragma unroll
    for (int j = 0; j < 4; ++j) o4[j] = (bf16_t)t[tx * 4 + j][ty + 16 * i];
    *(bf16x4*)(out + (size_t)(tc0 + ty + 16 * i) * R + tr0 + tx * 4) = o4;
  }
}

// ---------------- 256x256 8-phase GEMM: C[M][N] = A[M][K] * Bt[N][K]^T ----------------
// 8 waves (4M x 2N), BK=64, 2 K-tiles per iteration, counted vmcnt(6), LDS 128KB.
// LDS k-swizzle: 16B granule ^= (row&7), applied on global_load_lds SOURCE + ds_read.
#define LDA(buf)                                                                          \
  {                                                                                       \
    const int sb_ = (((buf)*2 + (wr >> 1)) * 128 + (wr & 1) * 64) * 64;                   \
    _Pragma("unroll") for (int mf = 0; mf < 4; ++mf) {                                    \
      int row_ = mf * 16 + ci;                                                            \
      _Pragma("unroll") for (int ks = 0; ks < 2; ++ks)                                    \
          a[mf][ks] = *(const bf16x8*)&lds[sb_ + row_ * 64 +                              \
                                           ((ks * 32 + g * 8) ^ ((ci & 7) << 3))];       \
    }                                                                                     \
  }

#define LDB(buf, nf0, arr)                                                                \
  {                                                                                       \
    const int sb_ = 32768 + ((buf)*2 + wc) * 8192;                                        \
    _Pragma("unroll") for (int j = 0; j < 2; ++j) {                                       \
      int row_ = ((nf0) + j) * 16 + ci;                                                   \
      _Pragma("unroll") for (int ks = 0; ks < 2; ++ks)                                    \
          arr[j][ks] = *(const bf16x8*)&lds[sb_ + row_ * 64 +                             \
                                            ((ks * 32 + g * 8) ^ ((ci & 7) << 3))];      \
    }                                                                                     \
  }

#define MM(arr, NFP)                                                                      \
  {                                                                                       \
    __builtin_amdgcn_s_setprio(1);                                                        \
    _Pragma("unroll") for (int mf = 0; mf < 4; ++mf)                                      \
        _Pragma("unroll") for (int j = 0; j < 2; ++j)                                     \
            _Pragma("unroll") for (int ks = 0; ks < 2; ++ks)                              \
                acc[mf][(NFP) + j] =                                                      \
        MFMA16(a[mf][ks], arr[j][ks], acc[mf][(NFP) + j]);                                \
    __builtin_amdgcn_s_setprio(0);                                                        \
  }

template <int WRITE_BF16>
__global__ __launch_bounds__(512) void gemm8(const bf16_t* __restrict__ A,
                                             const bf16_t* __restrict__ Bt,
                                             void* __restrict__ Cv,
                                             int M, int N, int K, int ntn) {
  __shared__ alignas(16) bf16_t lds[65536];  // A: [0,32768), B: [32768,65536)
  (void)M;
  const int tid = threadIdx.x;
  const int lane = tid & 63, w = tid >> 6;
  const int wr = w >> 1, wc = w & 1;  // 4 M-waves x 2 N-waves
  const int g = lane >> 4, ci = lane & 15;
  // XCD-bijective block swizzle (gridDim.x % 8 == 0)
  const int cpx = gridDim.x >> 3;
  const int wg = ((int)blockIdx.x & 7) * cpx + ((int)blockIdx.x >> 3);
  const int m0 = (wg / ntn) * 256, n0 = (wg % ntn) * 256;
  const int ksw = ((lane & 7) ^ (lane >> 3)) << 3;  // swizzled source granule

  auto stage = [&](const bf16_t* src, int ldsbase) {  // 128 rows x 64 k -> slot
#pragma unroll
    for (int j = 0; j < 2; ++j)
      GLOAD_LDS16(src + (size_t)(j * 64 + w * 8 + (lane >> 3)) * K + ksw,
                  (char*)&lds[ldsbase + (j * 64 + w * 8) * 64]);
  };

  bf16x8 a[4][2], b0[2][2], b1[2][2];
  f32x4 acc[4][8];
#pragma unroll
  for (int mf = 0; mf < 4; ++mf)
#pragma unroll
    for (int nf = 0; nf < 8; ++nf) acc[mf][nf] = f32x4{0.f, 0.f, 0.f, 0.f};

  // ---- prologue: stage kt0 (4 halves), vmcnt(4), kt1 (3 halves), vmcnt(6) ----
  stage(A + (size_t)m0 * K, 0);                       // A(0,0)
  stage(A + (size_t)(m0 + 128) * K, 8192);            // A(0,1)
  stage(Bt + (size_t)n0 * K, 32768);                  // B(0,0)
  stage(Bt + (size_t)(n0 + 128) * K, 40960);          // B(0,1)
  WAIT_VM4;
  stage(A + (size_t)m0 * K + 64, 16384);              // A(1,0)
  stage(A + (size_t)(m0 + 128) * K + 64, 24576);      // A(1,1)
  stage(Bt + (size_t)n0 * K + 64, 49152);             // B(1,0)
  WAIT_VM6;
  BARRIER;

  const int NT2 = K >> 7;  // iterations of 2 K-tiles
  for (int i = 0; i < NT2; ++i) {
    const int keb = i << 7;
    int e2 = keb + 128;
    if (e2 > K - 64) e2 = K - 64;
    int o2 = keb + 192;
    if (o2 > K - 64) o2 = K - 64;
    // ---- ph1: read A(buf0)+B(buf0,nf0-3); stage kt_o.b1 ----
    LDA(0) LDB(0, 0, b0) LDB(0, 2, b1)
    stage(Bt + (size_t)(n0 + 128) * K + keb + 64, 57344);
    BARRIER; WAIT_LGKM0;
    MM(b0, 0)
    BARRIER;
    // ---- ph2: read B(buf0,nf4-5); stage e'.a0 ----
    LDB(0, 4, b0)
    stage(A + (size_t)m0 * K + e2, 0);
    BARRIER; WAIT_LGKM0;
    MM(b1, 2)
    BARRIER;
    // ---- ph3: read B(buf0,nf6-7); stage e'.a1 ----
    LDB(0, 6, b1)
    stage(A + (size_t)(m0 + 128) * K + e2, 8192);
    BARRIER; WAIT_LGKM0;
    MM(b0, 4)
    BARRIER;
    // ---- ph4: stage e'.b0; vmcnt(6) guards buf1 reads at ph5 ----
    stage(Bt + (size_t)n0 * K + e2, 32768);
    BARRIER; WAIT_LGKM0;
    MM(b1, 6)
    WAIT_VM6;
    BARRIER;
    // ---- ph5: read A(buf1)+B(buf1,nf0-3); stage e'.b1 ----
    LDA(1) LDB(1, 0, b0) LDB(1, 2, b1)
    stage(Bt + (size_t)(n0 + 128) * K + e2, 40960);
    BARRIER; WAIT_LGKM0;
    MM(b0, 0)
    BARRIER;
    // ---- ph6: read B(buf1,nf4-5); stage o'.a0 ----
    LDB(1, 4, b0)
    stage(A + (size_t)m0 * K + o2, 16384);
    BARRIER; WAIT_LGKM0;
    MM(b1, 2)
    BARRIER;
    // ---- ph7: read B(buf1,nf6-7); stage o'.a1 ----
    LDB(1, 6, b1)
    stage(A + (size_t)(m0 + 128) * K + o2, 24576);
    BARRIER; WAIT_LGKM0;
    MM(b0, 4)
    BARRIER;
    // ---- ph8: stage o'.b0; vmcnt(6) guards buf0 reads at next ph1 ----
    stage(Bt + (size_t)n0 * K + o2, 49152);
    BARRIER; WAIT_LGKM0;
    MM(b1, 6)
    WAIT_VM6;
    BARRIER;
  }
  WAIT_VM0;

  // ---- epilogue: D row = (l>>4)*4 + r, col = l&15 ----
#pragma unroll
  for (int mf = 0; mf < 4; ++mf) {
#pragma unroll
    for (int nf = 0; nf < 8; ++nf) {
      int grow = m0 + wr * 64 + mf * 16 + g * 4;
      int gcol = n0 + wc * 128 + nf * 16 + ci;
#pragma unroll
      for (int r = 0; r < 4; ++r) {
        if (WRITE_BF16)
          ((bf16_t*)Cv)[(size_t)(grow + r) * N + gcol] = (bf16_t)acc[mf][nf][r];
        else
          ((float*)Cv)[(size_t)(grow + r) * N + gcol] = acc[mf][nf][r];
      }
    }
  }
}

// ---------------- RoPE + repack: fused QKV [token][6144] -> per-head [B,H,N,D] ----------------
__global__ __launch_bounds__(256) void rope_pack(const bf16_t* __restrict__ QKV,
                                                 const int* __restrict__ pos,
                                                 bf16_t* __restrict__ Qr,
                                                 bf16_t* __restrict__ Kr,
                                                 bf16_t* __restrict__ Vr) {
  int unit = blockIdx.x * 4 + (threadIdx.x >> 6);
  int lane = threadIdx.x & 63;
  int token = unit / 48, slot = unit % 48;
  int b = token >> 11, n = token & 2047;
  const bf16_t* base = QKV + (size_t)token * 6144;
  if (slot < 40) {
    float p = (float)pos[token];
    float inv = exp2f(-(float)lane * 0.20762050593045702f);
    float ang = p * inv;
    float sn, cs;
    sincosf(ang, &sn, &cs);
    const bf16_t* src;
    bf16_t* dst;
    if (slot < 32) {
      src = base + slot * 128;
      dst = Qr + ((size_t)(b * 32 + slot) * 2048 + n) * 128;
    } else {
      int kvh = slot - 32;
      src = base + 4096 + kvh * 128;
      dst = Kr + ((size_t)(b * 8 + kvh) * 2048 + n) * 128;
    }
    float x0 = (float)src[lane], x1 = (float)src[lane + 64];
    dst[lane] = (bf16_t)(x0 * cs - x1 * sn);
    dst[lane + 64] = (bf16_t)(x1 * cs + x0 * sn);
  } else {
    int kvh = slot - 40;
    const bf16_t* src = base + 5120 + kvh * 128;
    bf16_t* dst = Vr + ((size_t)(b * 8 + kvh) * 2048 + n) * 128;
    dst[lane] = src[lane];
    dst[lane + 64] = src[lane + 64];
  }
}

// ---------------- flash attention: 8 waves/block, paired q-tiles (balanced causal) ----
__global__ __launch_bounds__(512) void attn_kernel(const bf16_t* __restrict__ Q,
                                                   const bf16_t* __restrict__ K,
                                                   const bf16_t* __restrict__ V,
                                                   bf16_t* __restrict__ O) {
  const float scale = 0.08838834764831845f;  // 1/sqrt(128)
  __shared__ alignas(16) bf16_t Kl[64 * 128];    // swizzled [kv][d]
  __shared__ alignas(16) bf16_t Vt[128 * 64];    // swizzled [d][kv]
  __shared__ alignas(16) bf16_t Pl[8][32 * 64];  // per-wave swizzled [q][kv]
  const int tid = threadIdx.x;
  const int lane = tid & 63, w = tid >> 6;
  const int g = lane >> 4, ci = lane & 15;
  const int hb = blockIdx.y;  // b*32 + h
  const int b = hb >> 5, h = hb & 31, kvh = h >> 2;
  const int p = blockIdx.x;  // pair index 0..7
  const int qtB = 15 - p;
  const int qr[2] = {p * 128 + w * 16, qtB * 128 + w * 16};
  const bf16_t* Qh = Q + (size_t)hb * 2048 * 128;
  const bf16_t* Kh = K + (size_t)(b * 8 + kvh) * 2048 * 128;
  const bf16_t* Vh = V + (size_t)(b * 8 + kvh) * 2048 * 128;

  bf16x8 bq[2][4];
#pragma unroll
  for (int qb = 0; qb < 2; ++qb)
#pragma unroll
    for (int ks = 0; ks < 4; ++ks)
      bq[qb][ks] = *(const bf16x8*)(Qh + (size_t)(qr[qb] + ci) * 128 + ks * 32 + g * 8);

  f32x4 o[2][8];
#pragma unroll
  for (int qb = 0; qb < 2; ++qb)
#pragma unroll
    for (int nb = 0; nb < 8; ++nb) o[qb][nb] = f32x4{0.f, 0.f, 0.f, 0.f};
  float mrow[2] = {-1e30f, -1e30f};
  float lrow[2] = {0.f, 0.f};

  const int nt = (qtB + 1) * 2;
  for (int t = 0; t < nt; ++t) {
    const int kv0 = t * 64;
    __syncthreads();
#pragma unroll
    for (int i = 0; i < 2; ++i) {
      int c = tid + i * 512;
      int row = c >> 4, kc = (c & 15) * 8;
      bf16x8 kx = *(const bf16x8*)(Kh + (size_t)(kv0 + row) * 128 + kc);
      int sw = ((row ^ (row >> 3)) & 7) << 4;
      *(bf16x8*)((char*)Kl + row * 256 + ((kc * 2) ^ sw)) = kx;
    }
    {
      int kq = tid >> 5, dq = tid & 31;
      bf16x4 rv[4];
#pragma unroll
      for (int rr = 0; rr < 4; ++rr)
        rv[rr] = *(const bf16x4*)(Vh + (size_t)(kv0 + kq * 4 + rr) * 128 + dq * 4);
#pragma unroll
      for (int jj = 0; jj < 4; ++jj) {
        int d = dq * 4 + jj;
        bf16x4 cv;
#pragma unroll
        for (int rr = 0; rr < 4; ++rr) cv[rr] = rv[rr][jj];
        int sw = ((d ^ (d >> 3)) & 7) << 4;
        *(bf16x4*)((char*)Vt + d * 128 + ((kq * 8) ^ sw)) = cv;
      }
    }
    __syncthreads();

    bool act[2] = {kv0 <= qr[0] + 15, kv0 <= qr[1] + 15};
#pragma unroll
    for (int qb = 0; qb < 2; ++qb) {
      if (!act[qb]) continue;
      f32x4 st[4];
#pragma unroll
      for (int kvb = 0; kvb < 4; ++kvb) st[kvb] = f32x4{0.f, 0.f, 0.f, 0.f};
      __builtin_amdgcn_s_setprio(1);
#pragma unroll
      for (int kvb = 0; kvb < 4; ++kvb) {
        int row = kvb * 16 + ci;
        int sw = ((row ^ (row >> 3)) & 7) << 4;
#pragma unroll
        for (int ks = 0; ks < 4; ++ks) {
          bf16x8 ak = *(const bf16x8*)((char*)Kl + row * 256 + ((ks * 64 + g * 16) ^ sw));
          st[kvb] = MFMA16(ak, bq[qb][ks], st[kvb]);
        }
      }
      __builtin_amdgcn_s_setprio(0);
      const int q = qr[qb] + ci;
      const bool needmask = (kv0 + 63 > qr[qb]);
      float pv[16];
      float pm = -1e30f;
#pragma unroll
      for (int kvb = 0; kvb < 4; ++kvb)
#pragma unroll
        for (int r = 0; r < 4; ++r) {
          float v = st[kvb][r] * scale;
          if (needmask && (kv0 + kvb * 16 + 4 * g + r > q)) v = -1e30f;
          pv[kvb * 4 + r] = v;
          pm = fmaxf(pm, v);
        }
      pm = fmaxf(pm, __shfl_xor(pm, 16));
      pm = fmaxf(pm, __shfl_xor(pm, 32));
      float mnew = fmaxf(mrow[qb], pm);
      float fs = __expf(mrow[qb] - mnew);
      mrow[qb] = mnew;
      float ps = 0.f;
#pragma unroll
      for (int e = 0; e < 16; ++e) {
        pv[e] = __expf(pv[e] - mnew);
        ps += pv[e];
      }
      ps += __shfl_xor(ps, 16);
      ps += __shfl_xor(ps, 32);
      lrow[qb] = lrow[qb] * fs + ps;
      int prow = qb * 16 + ci;
      int swp = ((prow ^ (prow >> 3)) & 7) << 4;
#pragma unroll
      for (int kvb = 0; kvb < 4; ++kvb) {
        bf16x4 pk;
#pragma unroll
        for (int r = 0; r < 4; ++r) pk[r] = (bf16_t)pv[kvb * 4 + r];
        *(bf16x4*)((char*)&Pl[w][0] + prow * 128 + (((kvb * 16 + 4 * g) * 2) ^ swp)) = pk;
      }
      float fo[4];
#pragma unroll
      for (int r = 0; r < 4; ++r) fo[r] = __shfl(fs, 4 * g + r);
#pragma unroll
      for (int nb = 0; nb < 8; ++nb)
#pragma unroll
        for (int r = 0; r < 4; ++r) o[qb][nb][r] *= fo[r];
    }
    bf16x8 pa[2][2];
#pragma unroll
    for (int qb = 0; qb < 2; ++qb) {
      if (!act[qb]) continue;
      int prow = qb * 16 + ci;
      int swp = ((prow ^ (prow >> 3)) & 7) << 4;
#pragma unroll
      for (int ks = 0; ks < 2; ++ks)
        pa[qb][ks] = *(const bf16x8*)((char*)&Pl[w][0] + prow * 128 + ((ks * 64 + g * 16) ^ swp));
    }
    __builtin_amdgcn_s_setprio(1);
#pragma unroll
    for (int nb = 0; nb < 8; ++nb) {
      int d = nb * 16 + ci;
      int sw = ((d ^ (d >> 3)) & 7) << 4;
      bf16x8 bv0 = *(const bf16x8*)((char*)Vt + d * 128 + ((g * 16) ^ sw));
      bf16x8 bv1 = *(const bf16x8*)((char*)Vt + d * 128 + ((64 + g * 16) ^ sw));
#pragma unroll
      for (int qb = 0; qb < 2; ++qb) {
        if (!act[qb]) continue;
        o[qb][nb] = MFMA16(pa[qb][0], bv0, o[qb][nb]);
        o[qb][nb] = MFMA16(pa[qb][1], bv1, o[qb][nb]);
      }
    }
    __builtin_amdgcn_s_setprio(0);
  }
#pragma unroll
  for (int qb = 0; qb < 2; ++qb) {
    float linv = 1.0f / lrow[qb];
    float lv[4];
#pragma unroll
    for (int r = 0; r < 4; ++r) lv[r] = __shfl(linv, 4 * g + r);
#pragma unroll
    for (int r = 0; r < 4; ++r) {
      int n = qr[qb] + 4 * g + r;
      bf16_t* op = O + (size_t)(b * 2048 + n) * 4096 + h * 128;
#pragma unroll
      for (int nb = 0; nb < 8; ++nb) op[nb * 16 + ci] = (bf16_t)(o[qb][nb][r] * lv[r]);
    }
  }
}

extern "C" void kernel_launch(void* const* d_in, const int* in_sizes, int n_in,
                              void* d_out, int out_size, void* d_ws, size_t ws_size,
                              hipStream_t stream) {
  (void)in_sizes; (void)n_in; (void)out_size; (void)ws_size;
  const float* X = (const float*)d_in[0];
  const int* pos = (const int*)d_in[1];
  const float* Wq = (const float*)d_in[2];
  const float* Wk = (const float*)d_in[3];
  const float* Wv = (const float*)d_in[4];
  const float* Wo = (const float*)d_in[5];
  float* out = (float*)d_out;

  char* w = (char*)d_ws;
  auto carve = [&](size_t bytes) {
    void* p = (void*)w;
    w += (bytes + 255) & ~(size_t)255;
    return p;
  };
  const size_t T = 4096;  // B*N tokens
  bf16_t* Xbf    = (bf16_t*)carve(T * 4096 * 2);
  bf16_t* WqkvT  = (bf16_t*)carve(6144ull * 4096 * 2);  // [Wq;Wk;Wv] transposed
  bf16_t* WoT    = (bf16_t*)carve(4096ull * 4096 * 2);
  bf16_t* QKVraw = (bf16_t*)carve(T * 6144 * 2);
  bf16_t* Qr     = (bf16_t*)carve(T * 4096 * 2);
  bf16_t* Kr     = (bf16_t*)carve(T * 1024 * 2);
  bf16_t* Vr     = (bf16_t*)carve(T * 1024 * 2);
  bf16_t* Obf    = (bf16_t*)carve(T * 4096 * 2);

  cvt_bf16<<<2048, 256, 0, stream>>>(X, Xbf, (int)(T * 4096 / 4));
  transpose_cvt<<<dim3(64, 64), 256, 0, stream>>>(Wq, WqkvT, 4096, 4096);
  transpose_cvt<<<dim3(16, 64), 256, 0, stream>>>(Wk, WqkvT + 4096ull * 4096, 4096, 1024);
  transpose_cvt<<<dim3(16, 64), 256, 0, stream>>>(Wv, WqkvT + 5120ull * 4096, 4096, 1024);
  transpose_cvt<<<dim3(64, 64), 256, 0, stream>>>(Wo, WoT, 4096, 4096);

  // fused QKV projection: [4096 tokens][6144], 16x24 tiles of 256^2
  gemm8<1><<<384, 512, 0, stream>>>(Xbf, WqkvT, QKVraw, 4096, 6144, 4096, 24);

  rope_pack<<<(int)(T * 48 / 4), 256, 0, stream>>>(QKVraw, pos, Qr, Kr, Vr);

  attn_kernel<<<dim3(8, 64), 512, 0, stream>>>(Qr, Kr, Vr, Obf);

  // O projection: 16x16 tiles of 256^2
  gemm8<0><<<256, 512, 0, stream>>>(Obf, WoT, out, 4096, 4096, 4096, 16);
}

// Round 5
// 582.822 us; speedup vs baseline: 2.4697x; 1.0122x over previous
//
#include <hip/hip_runtime.h>
#include <hip/hip_bf16.h>

typedef __bf16 bf16_t;
typedef float  f32x4  __attribute__((ext_vector_type(4)));
typedef bf16_t bf16x4 __attribute__((ext_vector_type(4)));
typedef bf16_t bf16x8 __attribute__((ext_vector_type(8)));

#define MFMA16(a, b, c) __builtin_amdgcn_mfma_f32_16x16x32_bf16((a), (b), (c), 0, 0, 0)

#define GLOAD_LDS16(g, l)                                                              \
  __builtin_amdgcn_global_load_lds((const __attribute__((address_space(1))) void*)(g), \
                                   (__attribute__((address_space(3))) void*)(l), 16, 0, 0)

#define BARRIER    __builtin_amdgcn_s_barrier()
#define WAIT_LGKM0 asm volatile("s_waitcnt lgkmcnt(0)" ::: "memory")
#define WAIT_LGKM8 asm volatile("s_waitcnt lgkmcnt(8)" ::: "memory")
#define WAIT_VM4   asm volatile("s_waitcnt vmcnt(4)" ::: "memory")
#define WAIT_VM0   asm volatile("s_waitcnt vmcnt(0)" ::: "memory")

// ---------------- elementwise f32 -> bf16 ----------------
__global__ __launch_bounds__(256) void cvt_bf16(const float* __restrict__ in,
                                                bf16_t* __restrict__ out, int n4) {
  int stride = gridDim.x * blockDim.x;
  for (int i = blockIdx.x * blockDim.x + threadIdx.x; i < n4; i += stride) {
    f32x4 v = ((const f32x4*)in)[i];
    bf16x4 o;
#pragma unroll
    for (int j = 0; j < 4; ++j) o[j] = (bf16_t)v[j];
    ((bf16x4*)out)[i] = o;
  }
}

// ---------------- transpose + convert: in[R][C] f32 -> out[C][R] bf16 ----------------
__global__ __launch_bounds__(256) void transpose_cvt(const float* __restrict__ in,
                                                     bf16_t* __restrict__ out,
                                                     int R, int C) {
  __shared__ float t[64][65];
  int tr0 = blockIdx.y * 64, tc0 = blockIdx.x * 64;
  int tx = threadIdx.x & 15, ty = threadIdx.x >> 4;
#pragma unroll
  for (int i = 0; i < 4; ++i) {
    f32x4 v = *(const f32x4*)(in + (size_t)(tr0 + ty + 16 * i) * C + tc0 + tx * 4);
#pragma unroll
    for (int j = 0; j < 4; ++j) t[ty + 16 * i][tx * 4 + j] = v[j];
  }
  __syncthreads();
#pragma unroll
  for (int i = 0; i < 4; ++i) {
    bf16x4 o4;
#pragma unroll
    for (int j = 0; j < 4; ++j) o4[j] = (bf16_t)t[tx * 4 + j][ty + 16 * i];
    *(bf16x4*)(out + (size_t)(tc0 + ty + 16 * i) * R + tr0 + tx * 4) = o4;
  }
}

// ---------------- 256x256 8-phase GEMM (m201 geometry): C = A * Bt^T ----------------
// 8 waves as 2M x 4N (per-wave 128x64). B frags read once per K-tile (8 b128, ph1);
// A quadrant (2mf x 2ks = 4 b128) per phase. Stage rotation: A(o)@ph1-2, B(e')@ph3-4,
// A(e')@ph5-6, B(o')@ph7-8; vmcnt(4) at ph4/ph8. LDS 128KB, swizzled 16B granules.
#define LDB8(bf)                                                                         \
  {                                                                                      \
    const int sb_ = bBase0 + (bf)*16384;                                                 \
    _Pragma("unroll") for (int nf = 0; nf < 4; ++nf) {                                   \
      int row_ = brow0 + nf * 16 + ci;                                                   \
      _Pragma("unroll") for (int ks = 0; ks < 2; ++ks)                                   \
          b[nf][ks] = *(const bf16x8*)&lds[sb_ + row_ * 64 + ((ks * 32 + g * 8) ^ co)];  \
    }                                                                                    \
  }

#define LDA4(bf, q)                                                                      \
  {                                                                                      \
    const int sb_ = aBase0 + (bf)*16384;                                                 \
    _Pragma("unroll") for (int j = 0; j < 2; ++j) {                                      \
      int row_ = ((q)*2 + j) * 16 + ci;                                                  \
      _Pragma("unroll") for (int ks = 0; ks < 2; ++ks)                                   \
          a[j][ks] = *(const bf16x8*)&lds[sb_ + row_ * 64 + ((ks * 32 + g * 8) ^ co)];   \
    }                                                                                    \
  }

#define MMQ(q)                                                                           \
  {                                                                                      \
    __builtin_amdgcn_s_setprio(1);                                                       \
    _Pragma("unroll") for (int j = 0; j < 2; ++j)                                        \
        _Pragma("unroll") for (int nf = 0; nf < 4; ++nf)                                 \
            _Pragma("unroll") for (int ks = 0; ks < 2; ++ks)                             \
                acc[(q)*2 + j][nf] = MFMA16(a[j][ks], b[nf][ks], acc[(q)*2 + j][nf]);    \
    __builtin_amdgcn_s_setprio(0);                                                       \
  }

template <int WRITE_BF16>
__global__ __launch_bounds__(512) void gemm8(const bf16_t* __restrict__ A,
                                             const bf16_t* __restrict__ Bt,
                                             void* __restrict__ Cv,
                                             int N, int K, int ntn) {
  __shared__ alignas(16) bf16_t lds[65536];  // A: [0,32768), B: [32768,65536)
  const int tid = threadIdx.x;
  const int lane = tid & 63, w = tid >> 6;
  const int wr = w >> 2, wc = w & 3;  // 2 M-waves x 4 N-waves
  const int g = lane >> 4, ci = lane & 15;
  const int cpx = gridDim.x >> 3;  // XCD-bijective swizzle (gridDim.x % 8 == 0)
  const int wg = ((int)blockIdx.x & 7) * cpx + ((int)blockIdx.x >> 3);
  const int m0 = (wg / ntn) * 256, n0 = (wg % ntn) * 256;
  const int ksw = ((lane & 7) ^ (lane >> 3)) << 3;  // swizzled source granule
  const int aBase0 = wr * 8192;
  const int bBase0 = 32768 + (wc >> 1) * 8192;
  const int brow0 = (wc & 1) * 64;
  const int co = (ci & 7) << 3;

  const bf16_t* As[2] = {A + (size_t)m0 * K, A + (size_t)(m0 + 128) * K};
  const bf16_t* Bs[2] = {Bt + (size_t)n0 * K, Bt + (size_t)(n0 + 128) * K};

  auto stage = [&](const bf16_t* src, int kk, int ldsbase) {  // 128 rows x 64 k
#pragma unroll
    for (int j = 0; j < 2; ++j)
      GLOAD_LDS16(src + (size_t)(j * 64 + w * 8 + (lane >> 3)) * K + kk + ksw,
                  (char*)&lds[ldsbase + (j * 64 + w * 8) * 64]);
  };

  bf16x8 a[2][2], b[4][2];
  f32x4 acc[8][4];
#pragma unroll
  for (int mf = 0; mf < 8; ++mf)
#pragma unroll
    for (int nf = 0; nf < 4; ++nf) acc[mf][nf] = f32x4{0.f, 0.f, 0.f, 0.f};

  // ---- prologue: buf0 = K-tile 0 (A+B), plus B of K-tile 64 (buf1) ----
  stage(As[0], 0, 0);
  stage(As[1], 0, 8192);
  stage(Bs[0], 0, 32768);
  stage(Bs[1], 0, 40960);
  stage(Bs[0], 64, 49152);
  stage(Bs[1], 64, 57344);
  WAIT_VM4;  // drain buf0's 4 stages; B(64) stays in flight
  BARRIER;

  const int NT2 = K >> 7;
  for (int i = 0; i < NT2; ++i) {
    const int keb = i << 7;
    const int kA1 = keb + 64;
    int e2 = keb + 128;
    if (e2 > K - 64) e2 = K - 64;
    int o2 = keb + 192;
    if (o2 > K - 64) o2 = K - 64;
    // ph1: buf0 q0 (a + all b = 12 reads); stage A(odd,h0) -> buf1
    LDA4(0, 0) LDB8(0)
    stage(As[0], kA1, 16384);
    WAIT_LGKM8;
    BARRIER; WAIT_LGKM0;
    MMQ(0)
    BARRIER;
    // ph2: buf0 q1; stage A(odd,h1)
    LDA4(0, 1)
    stage(As[1], kA1, 24576);
    BARRIER; WAIT_LGKM0;
    MMQ(1)
    BARRIER;
    // ph3: buf0 q2; stage B(e',h0)
    LDA4(0, 2)
    stage(Bs[0], e2, 32768);
    BARRIER; WAIT_LGKM0;
    MMQ(2)
    BARRIER;
    // ph4: buf0 q3; stage B(e',h1); vmcnt(4) readies buf1 (A@ph1-2, B@prev ph7-8)
    LDA4(0, 3)
    stage(Bs[1], e2, 40960);
    BARRIER; WAIT_LGKM0;
    MMQ(3)
    WAIT_VM4;
    BARRIER;
    // ph5: buf1 q0 (a + b); stage A(e',h0) -> buf0
    LDA4(1, 0) LDB8(1)
    stage(As[0], e2, 0);
    WAIT_LGKM8;
    BARRIER; WAIT_LGKM0;
    MMQ(0)
    BARRIER;
    // ph6: buf1 q1; stage A(e',h1)
    LDA4(1, 1)
    stage(As[1], e2, 8192);
    BARRIER; WAIT_LGKM0;
    MMQ(1)
    BARRIER;
    // ph7: buf1 q2; stage B(o',h0) -> buf1
    LDA4(1, 2)
    stage(Bs[0], o2, 49152);
    BARRIER; WAIT_LGKM0;
    MMQ(2)
    BARRIER;
    // ph8: buf1 q3; stage B(o',h1); vmcnt(4) readies buf0 (B@ph3-4, A@ph5-6)
    LDA4(1, 3)
    stage(Bs[1], o2, 57344);
    BARRIER; WAIT_LGKM0;
    MMQ(3)
    WAIT_VM4;
    BARRIER;
  }
  WAIT_VM0;

  // ---- epilogue: D row = (l>>4)*4 + r, col = l&15 ----
#pragma unroll
  for (int mf = 0; mf < 8; ++mf) {
#pragma unroll
    for (int nf = 0; nf < 4; ++nf) {
      int grow = m0 + wr * 128 + mf * 16 + g * 4;
      int gcol = n0 + wc * 64 + nf * 16 + ci;
#pragma unroll
      for (int r = 0; r < 4; ++r) {
        if (WRITE_BF16)
          ((bf16_t*)Cv)[(size_t)(grow + r) * N + gcol] = (bf16_t)acc[mf][nf][r];
        else
          ((float*)Cv)[(size_t)(grow + r) * N + gcol] = acc[mf][nf][r];
      }
    }
  }
}

// ---------------- RoPE + repack: fused QKV [token][6144] -> per-head [B,H,N,D] ----------------
__global__ __launch_bounds__(256) void rope_pack(const bf16_t* __restrict__ QKV,
                                                 const int* __restrict__ pos,
                                                 bf16_t* __restrict__ Qr,
                                                 bf16_t* __restrict__ Kr,
                                                 bf16_t* __restrict__ Vr) {
  int unit = blockIdx.x * 4 + (threadIdx.x >> 6);
  int lane = threadIdx.x & 63;
  int token = unit / 48, slot = unit % 48;
  int b = token >> 11, n = token & 2047;
  const bf16_t* base = QKV + (size_t)token * 6144;
  if (slot < 40) {
    float p = (float)pos[token];
    float inv = exp2f(-(float)lane * 0.20762050593045702f);
    float ang = p * inv;
    float sn, cs;
    sincosf(ang, &sn, &cs);
    const bf16_t* src;
    bf16_t* dst;
    if (slot < 32) {
      src = base + slot * 128;
      dst = Qr + ((size_t)(b * 32 + slot) * 2048 + n) * 128;
    } else {
      int kvh = slot - 32;
      src = base + 4096 + kvh * 128;
      dst = Kr + ((size_t)(b * 8 + kvh) * 2048 + n) * 128;
    }
    float x0 = (float)src[lane], x1 = (float)src[lane + 64];
    dst[lane] = (bf16_t)(x0 * cs - x1 * sn);
    dst[lane + 64] = (bf16_t)(x1 * cs + x0 * sn);
  } else {
    int kvh = slot - 40;
    const bf16_t* src = base + 5120 + kvh * 128;
    bf16_t* dst = Vr + ((size_t)(b * 8 + kvh) * 2048 + n) * 128;
    dst[lane] = src[lane];
    dst[lane + 64] = src[lane + 64];
  }
}

// ---------------- flash attention: 8 waves/block, paired q-tiles (balanced causal) ----
__global__ __launch_bounds__(512) void attn_kernel(const bf16_t* __restrict__ Q,
                                                   const bf16_t* __restrict__ K,
                                                   const bf16_t* __restrict__ V,
                                                   bf16_t* __restrict__ O) {
  const float scale = 0.08838834764831845f;  // 1/sqrt(128)
  __shared__ alignas(16) bf16_t Kl[64 * 128];    // swizzled [kv][d]
  __shared__ alignas(16) bf16_t Vt[128 * 64];    // swizzled [d][kv]
  __shared__ alignas(16) bf16_t Pl[8][32 * 64];  // per-wave swizzled [q][kv]
  const int tid = threadIdx.x;
  const int lane = tid & 63, w = tid >> 6;
  const int g = lane >> 4, ci = lane & 15;
  const int hb = blockIdx.y;  // b*32 + h
  const int b = hb >> 5, h = hb & 31, kvh = h >> 2;
  const int p = blockIdx.x;  // pair index 0..7
  const int qtB = 15 - p;
  const int qr[2] = {p * 128 + w * 16, qtB * 128 + w * 16};
  const bf16_t* Qh = Q + (size_t)hb * 2048 * 128;
  const bf16_t* Kh = K + (size_t)(b * 8 + kvh) * 2048 * 128;
  const bf16_t* Vh = V + (size_t)(b * 8 + kvh) * 2048 * 128;

  bf16x8 bq[2][4];
#pragma unroll
  for (int qb = 0; qb < 2; ++qb)
#pragma unroll
    for (int ks = 0; ks < 4; ++ks)
      bq[qb][ks] = *(const bf16x8*)(Qh + (size_t)(qr[qb] + ci) * 128 + ks * 32 + g * 8);

  f32x4 o[2][8];
#pragma unroll
  for (int qb = 0; qb < 2; ++qb)
#pragma unroll
    for (int nb = 0; nb < 8; ++nb) o[qb][nb] = f32x4{0.f, 0.f, 0.f, 0.f};
  float mrow[2] = {-1e30f, -1e30f};
  float lrow[2] = {0.f, 0.f};

  const int nt = (qtB + 1) * 2;
  for (int t = 0; t < nt; ++t) {
    const int kv0 = t * 64;
    __syncthreads();
#pragma unroll
    for (int i = 0; i < 2; ++i) {
      int c = tid + i * 512;
      int row = c >> 4, kc = (c & 15) * 8;
      bf16x8 kx = *(const bf16x8*)(Kh + (size_t)(kv0 + row) * 128 + kc);
      int sw = ((row ^ (row >> 3)) & 7) << 4;
      *(bf16x8*)((char*)Kl + row * 256 + ((kc * 2) ^ sw)) = kx;
    }
    {
      int kq = tid >> 5, dq = tid & 31;
      bf16x4 rv[4];
#pragma unroll
      for (int rr = 0; rr < 4; ++rr)
        rv[rr] = *(const bf16x4*)(Vh + (size_t)(kv0 + kq * 4 + rr) * 128 + dq * 4);
#pragma unroll
      for (int jj = 0; jj < 4; ++jj) {
        int d = dq * 4 + jj;
        bf16x4 cv;
#pragma unroll
        for (int rr = 0; rr < 4; ++rr) cv[rr] = rv[rr][jj];
        int sw = ((d ^ (d >> 3)) & 7) << 4;
        *(bf16x4*)((char*)Vt + d * 128 + ((kq * 8) ^ sw)) = cv;
      }
    }
    __syncthreads();

    bool act[2] = {kv0 <= qr[0] + 15, kv0 <= qr[1] + 15};
#pragma unroll
    for (int qb = 0; qb < 2; ++qb) {
      if (!act[qb]) continue;
      f32x4 st[4];
#pragma unroll
      for (int kvb = 0; kvb < 4; ++kvb) st[kvb] = f32x4{0.f, 0.f, 0.f, 0.f};
      __builtin_amdgcn_s_setprio(1);
#pragma unroll
      for (int kvb = 0; kvb < 4; ++kvb) {
        int row = kvb * 16 + ci;
        int sw = ((row ^ (row >> 3)) & 7) << 4;
#pragma unroll
        for (int ks = 0; ks < 4; ++ks) {
          bf16x8 ak = *(const bf16x8*)((char*)Kl + row * 256 + ((ks * 64 + g * 16) ^ sw));
          st[kvb] = MFMA16(ak, bq[qb][ks], st[kvb]);
        }
      }
      __builtin_amdgcn_s_setprio(0);
      const int q = qr[qb] + ci;
      const bool needmask = (kv0 + 63 > qr[qb]);
      float pv[16];
      float pm = -1e30f;
#pragma unroll
      for (int kvb = 0; kvb < 4; ++kvb)
#pragma unroll
        for (int r = 0; r < 4; ++r) {
          float v = st[kvb][r] * scale;
          if (needmask && (kv0 + kvb * 16 + 4 * g + r > q)) v = -1e30f;
          pv[kvb * 4 + r] = v;
          pm = fmaxf(pm, v);
        }
      pm = fmaxf(pm, __shfl_xor(pm, 16));
      pm = fmaxf(pm, __shfl_xor(pm, 32));
      // T13 defer-max: skip rescale when tile max is within 8 of running max
      const bool nskip = !__all((int)(pm <= mrow[qb] + 8.0f));
      const float mold = mrow[qb];
      float mnew = mold;
      float fs = 1.0f;
      if (nskip) {
        mnew = fmaxf(mold, pm);
        fs = __expf(mold - mnew);
        mrow[qb] = mnew;
      }
      float ps = 0.f;
#pragma unroll
      for (int e = 0; e < 16; ++e) {
        pv[e] = __expf(pv[e] - mnew);
        ps += pv[e];
      }
      ps += __shfl_xor(ps, 16);
      ps += __shfl_xor(ps, 32);
      lrow[qb] = (nskip ? lrow[qb] * fs : lrow[qb]) + ps;
      int prow = qb * 16 + ci;
      int swp = ((prow ^ (prow >> 3)) & 7) << 4;
#pragma unroll
      for (int kvb = 0; kvb < 4; ++kvb) {
        bf16x4 pk;
#pragma unroll
        for (int r = 0; r < 4; ++r) pk[r] = (bf16_t)pv[kvb * 4 + r];
        *(bf16x4*)((char*)&Pl[w][0] + prow * 128 + (((kvb * 16 + 4 * g) * 2) ^ swp)) = pk;
      }
      if (nskip) {
        float fo[4];
#pragma unroll
        for (int r = 0; r < 4; ++r) fo[r] = __shfl(fs, 4 * g + r);
#pragma unroll
        for (int nb = 0; nb < 8; ++nb)
#pragma unroll
          for (int r = 0; r < 4; ++r) o[qb][nb][r] *= fo[r];
      }
    }
    bf16x8 pa[2][2];
#pragma unroll
    for (int qb = 0; qb < 2; ++qb) {
      if (!act[qb]) continue;
      int prow = qb * 16 + ci;
      int swp = ((prow ^ (prow >> 3)) & 7) << 4;
#pragma unroll
      for (int ks = 0; ks < 2; ++ks)
        pa[qb][ks] = *(const bf16x8*)((char*)&Pl[w][0] + prow * 128 + ((ks * 64 + g * 16) ^ swp));
    }
    __builtin_amdgcn_s_setprio(1);
#pragma unroll
    for (int nb = 0; nb < 8; ++nb) {
      int d = nb * 16 + ci;
      int sw = ((d ^ (d >> 3)) & 7) << 4;
      bf16x8 bv0 = *(const bf16x8*)((char*)Vt + d * 128 + ((g * 16) ^ sw));
      bf16x8 bv1 = *(const bf16x8*)((char*)Vt + d * 128 + ((64 + g * 16) ^ sw));
#pragma unroll
      for (int qb = 0; qb < 2; ++qb) {
        if (!act[qb]) continue;
        o[qb][nb] = MFMA16(pa[qb][0], bv0, o[qb][nb]);
        o[qb][nb] = MFMA16(pa[qb][1], bv1, o[qb][nb]);
      }
    }
    __builtin_amdgcn_s_setprio(0);
  }
#pragma unroll
  for (int qb = 0; qb < 2; ++qb) {
    float linv = 1.0f / lrow[qb];
    float lv[4];
#pragma unroll
    for (int r = 0; r < 4; ++r) lv[r] = __shfl(linv, 4 * g + r);
#pragma unroll
    for (int r = 0; r < 4; ++r) {
      int n = qr[qb] + 4 * g + r;
      bf16_t* op = O + (size_t)(b * 2048 + n) * 4096 + h * 128;
#pragma unroll
      for (int nb = 0; nb < 8; ++nb) op[nb * 16 + ci] = (bf16_t)(o[qb][nb][r] * lv[r]);
    }
  }
}

extern "C" void kernel_launch(void* const* d_in, const int* in_sizes, int n_in,
                              void* d_out, int out_size, void* d_ws, size_t ws_size,
                              hipStream_t stream) {
  (void)in_sizes; (void)n_in; (void)out_size; (void)ws_size;
  const float* X = (const float*)d_in[0];
  const int* pos = (const int*)d_in[1];
  const float* Wq = (const float*)d_in[2];
  const float* Wk = (const float*)d_in[3];
  const float* Wv = (const float*)d_in[4];
  const float* Wo = (const float*)d_in[5];
  float* out = (float*)d_out;

  char* w = (char*)d_ws;
  auto carve = [&](size_t bytes) {
    void* p = (void*)w;
    w += (bytes + 255) & ~(size_t)255;
    return p;
  };
  const size_t T = 4096;  // B*N tokens
  bf16_t* Xbf    = (bf16_t*)carve(T * 4096 * 2);
  bf16_t* WqkvT  = (bf16_t*)carve(6144ull * 4096 * 2);  // [Wq;Wk;Wv] transposed
  bf16_t* WoT    = (bf16_t*)carve(4096ull * 4096 * 2);
  bf16_t* QKVraw = (bf16_t*)carve(T * 6144 * 2);
  bf16_t* Qr     = (bf16_t*)carve(T * 4096 * 2);
  bf16_t* Kr     = (bf16_t*)carve(T * 1024 * 2);
  bf16_t* Vr     = (bf16_t*)carve(T * 1024 * 2);
  bf16_t* Obf    = (bf16_t*)carve(T * 4096 * 2);

  cvt_bf16<<<2048, 256, 0, stream>>>(X, Xbf, (int)(T * 4096 / 4));
  transpose_cvt<<<dim3(64, 64), 256, 0, stream>>>(Wq, WqkvT, 4096, 4096);
  transpose_cvt<<<dim3(16, 64), 256, 0, stream>>>(Wk, WqkvT + 4096ull * 4096, 4096, 1024);
  transpose_cvt<<<dim3(16, 64), 256, 0, stream>>>(Wv, WqkvT + 5120ull * 4096, 4096, 1024);
  transpose_cvt<<<dim3(64, 64), 256, 0, stream>>>(Wo, WoT, 4096, 4096);

  // fused QKV projection: [4096 tokens][6144], 16x24 tiles of 256^2
  gemm8<1><<<384, 512, 0, stream>>>(Xbf, WqkvT, QKVraw, 6144, 4096, 24);

  rope_pack<<<(int)(T * 48 / 4), 256, 0, stream>>>(QKVraw, pos, Qr, Kr, Vr);

  attn_kernel<<<dim3(8, 64), 512, 0, stream>>>(Qr, Kr, Vr, Obf);

  // O projection: 16x16 tiles of 256^2
  gemm8<0><<<256, 512, 0, stream>>>(Obf, WoT, out, 4096, 4096, 16);
}